// Round 8
// baseline (579.256 us; speedup 1.0000x reference)
//
#include <hip/hip_runtime.h>
#include <hip/hip_fp16.h>
#include <math.h>

#define N_NODES 50000
#define N_EDGES 800000
#define NB      64
#define ND      64
#define ED      16
#define HID     128
#define NC      6
#define SCAN_BLOCKS ((N_NODES + 255) / 256)   // 196
#define GEMM_BLOCKS ((N_NODES + 63) / 64)     // 782

typedef _Float16 f16;
typedef f16  half8  __attribute__((ext_vector_type(8)));
typedef float floatx4 __attribute__((ext_vector_type(4)));

// ---------------- setup: zero deg + WeAe + fp16 weight transpose, one launch ----------------
__global__ void k_setup(const float* __restrict__ pW, const float* __restrict__ W0,
                        const float* __restrict__ W1, const float* __restrict__ W2,
                        const float* __restrict__ We0, const float* __restrict__ ae0,
                        const float* __restrict__ We1, const float* __restrict__ ae1,
                        const float* __restrict__ We2, const float* __restrict__ ae2,
                        int* __restrict__ deg, float* __restrict__ WeAe,
                        f16* __restrict__ Wtp, f16* __restrict__ Wt0,
                        f16* __restrict__ Wt1, f16* __restrict__ Wt2) {
    int i = blockIdx.x * 256 + threadIdx.x;
    if (i < N_NODES) deg[i] = 0;
    if (i < 128 * 64) {
        int n = i / 64, k = i % 64;
        Wtp[i] = (f16)pW[k * 128 + n];
    }
    if (i < 128 * 128) {
        int n = i / 128, k = i % 128;
        Wt0[i] = (f16)W0[k * 128 + n];
        Wt1[i] = (f16)W1[k * 128 + n];
        Wt2[i] = (f16)W2[k * 128 + n];
    }
    if (i >= 60000 && i < 60144) {
        int t = i - 60000;
        if (t < 64) {
            int k = t >> 2, h = t & 3;
            float s = 0.f;
            for (int c = 0; c < 32; c++) s += We0[k * HID + h * 32 + c] * ae0[h * 32 + c];
            WeAe[k * 9 + h] = s;
        } else if (t < 128) {
            int tt = t - 64;
            int k = tt >> 2, h = tt & 3;
            float s = 0.f;
            for (int c = 0; c < 32; c++) s += We1[k * HID + h * 32 + c] * ae1[h * 32 + c];
            WeAe[k * 9 + 4 + h] = s;
        } else {
            int k = t - 128;
            float s = 0.f;
            for (int c = 0; c < HID; c++) s += We2[k * HID + c] * ae2[c];
            WeAe[k * 9 + 8] = s;
        }
    }
}

// ---------------- MFMA GEMM: out = act[M,K] @ W[K,128] ----------------
template <int K, int MODE>
__global__ __launch_bounds__(256) void k_gemm(
        const float* __restrict__ act, const f16* __restrict__ Wt,
        const float* __restrict__ bias, const float* __restrict__ as_,
        const float* __restrict__ ad_, float* __restrict__ hout,
        __half* __restrict__ xp, float* __restrict__ al_src,
        float* __restrict__ al_dst) {
    constexpr int KP = K + 8;
    __shared__ __align__(16) f16 A[64 * KP];
    __shared__ float part_s[4][64];
    __shared__ float part_d[4][64];
    int tid = threadIdx.x;
    int base = blockIdx.x * 64;

    constexpr int NV = 64 * K / 4 / 256;
    #pragma unroll
    for (int i = 0; i < NV; i++) {
        int v = tid + i * 256;
        int row = v / (K / 4);
        int k4 = v % (K / 4);
        float4 xv = make_float4(0.f, 0.f, 0.f, 0.f);
        if (base + row < N_NODES)
            xv = *(const float4*)(act + (size_t)(base + row) * K + k4 * 4);
        f16* dp = &A[row * KP + k4 * 4];
        dp[0] = (f16)xv.x; dp[1] = (f16)xv.y; dp[2] = (f16)xv.z; dp[3] = (f16)xv.w;
    }
    __syncthreads();

    int w = tid >> 6, l = tid & 63;
    int lm = l & 15, q = l >> 4;
    floatx4 acc[4][2];
    #pragma unroll
    for (int mt = 0; mt < 4; mt++)
        #pragma unroll
        for (int j = 0; j < 2; j++)
            acc[mt][j] = (floatx4){0.f, 0.f, 0.f, 0.f};

    #pragma unroll
    for (int kt = 0; kt < K / 32; kt++) {
        int ko = kt * 32 + q * 8;
        half8 b0 = *(const half8*)(Wt + (size_t)(w * 32 + lm) * K + ko);
        half8 b1 = *(const half8*)(Wt + (size_t)(w * 32 + 16 + lm) * K + ko);
        #pragma unroll
        for (int mt = 0; mt < 4; mt++) {
            half8 a = *(const half8*)(&A[(mt * 16 + lm) * KP + ko]);
            acc[mt][0] = __builtin_amdgcn_mfma_f32_16x16x32_f16(a, b0, acc[mt][0], 0, 0, 0);
            acc[mt][1] = __builtin_amdgcn_mfma_f32_16x16x32_f16(a, b1, acc[mt][1], 0, 0, 0);
        }
    }

    if (MODE == 0) {
        float b0 = bias[w * 32 + lm];
        float b1 = bias[w * 32 + 16 + lm];
        #pragma unroll
        for (int mt = 0; mt < 4; mt++)
            #pragma unroll
            for (int r = 0; r < 4; r++) {
                int row = mt * 16 + q * 4 + r;
                if (base + row < N_NODES) {
                    hout[(size_t)(base + row) * HID + w * 32 + lm]      = fmaxf(acc[mt][0][r] + b0, 0.f);
                    hout[(size_t)(base + row) * HID + w * 32 + 16 + lm] = fmaxf(acc[mt][1][r] + b1, 0.f);
                }
            }
    } else {
        float a0 = as_[w * 32 + lm], a1 = as_[w * 32 + 16 + lm];
        float e0 = ad_[w * 32 + lm], e1 = ad_[w * 32 + 16 + lm];
        float ps[4][4], pd[4][4];
        #pragma unroll
        for (int mt = 0; mt < 4; mt++)
            #pragma unroll
            for (int r = 0; r < 4; r++) {
                ps[mt][r] = acc[mt][0][r] * a0 + acc[mt][1][r] * a1;
                pd[mt][r] = acc[mt][0][r] * e0 + acc[mt][1][r] * e1;
            }
        #pragma unroll
        for (int off = 1; off < 16; off <<= 1)
            #pragma unroll
            for (int mt = 0; mt < 4; mt++)
                #pragma unroll
                for (int r = 0; r < 4; r++) {
                    ps[mt][r] += __shfl_xor(ps[mt][r], off, 64);
                    pd[mt][r] += __shfl_xor(pd[mt][r], off, 64);
                }
        if (MODE == 1) {
            if (lm == 0)
                #pragma unroll
                for (int mt = 0; mt < 4; mt++)
                    #pragma unroll
                    for (int r = 0; r < 4; r++) {
                        int n = base + mt * 16 + q * 4 + r;
                        if (n < N_NODES) {
                            al_src[n * 4 + w] = ps[mt][r];
                            al_dst[n * 4 + w] = pd[mt][r];
                        }
                    }
        } else {
            if (lm == 0)
                #pragma unroll
                for (int mt = 0; mt < 4; mt++)
                    #pragma unroll
                    for (int r = 0; r < 4; r++) {
                        part_s[w][mt * 16 + q * 4 + r] = ps[mt][r];
                        part_d[w][mt * 16 + q * 4 + r] = pd[mt][r];
                    }
        }
        __syncthreads();
        #pragma unroll
        for (int mt = 0; mt < 4; mt++)
            #pragma unroll
            for (int r = 0; r < 4; r++) {
                int row = mt * 16 + q * 4 + r;
                A[row * KP + w * 32 + lm]      = (f16)acc[mt][0][r];
                A[row * KP + w * 32 + 16 + lm] = (f16)acc[mt][1][r];
            }
        if (MODE == 2 && tid < 64) {
            int n = base + tid;
            if (n < N_NODES) {
                al_src[n] = part_s[0][tid] + part_s[1][tid] + part_s[2][tid] + part_s[3][tid];
                al_dst[n] = part_d[0][tid] + part_d[1][tid] + part_d[2][tid] + part_d[3][tid];
            }
        }
        __syncthreads();
        #pragma unroll
        for (int i = 0; i < 4; i++) {
            int v = tid + i * 256;
            int row = v >> 4, c8 = v & 15;
            if (base + row < N_NODES) {
                float4 hv = *(const float4*)(&A[row * KP + c8 * 8]);
                *reinterpret_cast<float4*>(reinterpret_cast<char*>(xp) +
                    ((size_t)(base + row) * HID + c8 * 8) * 2) = hv;
            }
        }
    }
}

// ---------------- degree + per-edge rank ----------------
__global__ void k_deg(const int* __restrict__ dst, int* __restrict__ deg,
                      int* __restrict__ rank) {
    int e = blockIdx.x * blockDim.x + threadIdx.x;
    if (e < N_EDGES) rank[e] = atomicAdd(&deg[dst[e]], 1);
}

__global__ void k_scanA(const int* __restrict__ deg, int* __restrict__ bsum) {
    __shared__ int wsu[4];
    int t = threadIdx.x;
    int i = blockIdx.x * 256 + t;
    int d = (i < N_NODES) ? deg[i] : 0;
    int v = d;
    #pragma unroll
    for (int o = 32; o > 0; o >>= 1) v += __shfl_xor(v, o, 64);
    if ((t & 63) == 0) wsu[t >> 6] = v;
    __syncthreads();
    if (t == 0) bsum[blockIdx.x] = wsu[0] + wsu[1] + wsu[2] + wsu[3];
}

__global__ void k_scanB(const int* __restrict__ bsum, int* __restrict__ bpre,
                        int* __restrict__ offs) {
    __shared__ int sc[256];
    int t = threadIdx.x;
    int d = (t < SCAN_BLOCKS) ? bsum[t] : 0;
    sc[t] = d;
    __syncthreads();
    for (int o = 1; o < 256; o <<= 1) {
        int v = (t >= o) ? sc[t - o] : 0;
        __syncthreads();
        sc[t] += v;
        __syncthreads();
    }
    if (t < SCAN_BLOCKS) bpre[t] = sc[t] - d;
    if (t == 0) offs[N_NODES] = N_EDGES;
}

__global__ void k_scanC(const int* __restrict__ deg, const int* __restrict__ bpre,
                        int* __restrict__ offs) {
    __shared__ int sc[256];
    int t = threadIdx.x;
    int i = blockIdx.x * 256 + t;
    int d = (i < N_NODES) ? deg[i] : 0;
    sc[t] = d;
    __syncthreads();
    for (int o = 1; o < 256; o <<= 1) {
        int v = (t >= o) ? sc[t - o] : 0;
        __syncthreads();
        sc[t] += v;
        __syncthreads();
    }
    if (i < N_NODES) offs[i] = bpre[blockIdx.x] + sc[t] - d;
}

// ---------------- build packed CSR records (atomic-free, full-line scatter) ----------------
// rec[p]: q0={r0..r3}(L0) q1={r4..r7}(L1) q2={r8, src, dst, 0} q3=0
__global__ void k_edge_build(const int* __restrict__ src, const int* __restrict__ dst,
                             const int* __restrict__ rank, const int* __restrict__ offs,
                             const float* __restrict__ ea, const float* __restrict__ WeAe,
                             float4* __restrict__ rec) {
    __shared__ float w[ED * 9];
    __shared__ float4 rs[256][4];
    __shared__ int rp[256];
    int tid = threadIdx.x;
    if (tid < ED * 9) w[tid] = WeAe[tid];
    __syncthreads();
    int e = blockIdx.x * 256 + tid;
    if (e < N_EDGES) {
        float ev[ED];
        const float4* ep4 = reinterpret_cast<const float4*>(ea + (size_t)e * ED);
        #pragma unroll
        for (int q = 0; q < 4; q++) {
            float4 v = ep4[q];
            ev[q * 4 + 0] = v.x; ev[q * 4 + 1] = v.y;
            ev[q * 4 + 2] = v.z; ev[q * 4 + 3] = v.w;
        }
        float r[9];
        #pragma unroll
        for (int j = 0; j < 9; j++) r[j] = 0.f;
        #pragma unroll
        for (int k = 0; k < ED; k++) {
            float evk = ev[k];
            #pragma unroll
            for (int j = 0; j < 9; j++) r[j] += evk * w[k * 9 + j];
        }
        int d = dst[e], s = src[e];
        rp[tid] = offs[d] + rank[e];
        rs[tid][0] = make_float4(r[0], r[1], r[2], r[3]);
        rs[tid][1] = make_float4(r[4], r[5], r[6], r[7]);
        rs[tid][2] = make_float4(r[8], __int_as_float(s), __int_as_float(d), 0.f);
        rs[tid][3] = make_float4(0.f, 0.f, 0.f, 0.f);
    } else {
        rp[tid] = -1;
    }
    __syncthreads();
    int g0 = tid >> 2, q = tid & 3;
    #pragma unroll
    for (int rr = 0; rr < 4; rr++) {
        int g = rr * 64 + g0;
        int p = rp[g];
        if (p >= 0) rec[(size_t)p * 4 + q] = rs[g][q];
    }
}

// ---------------- fused agg: on-the-fly edge weights + gather + softmax-norm + LN + ELU + res ----
// wave per node; lane = side(2b) | cl(4b); cl handles 8 channels c=cl*8 (16B fp16); 4 sides
template <int H, int SLOT>
__global__ void k_node_agg(const int* __restrict__ offs, const float4* __restrict__ rec,
                           const float* __restrict__ al_src, const float* __restrict__ al_dst,
                           const __half* __restrict__ xp, const float* __restrict__ bias,
                           const float* __restrict__ g, const float* __restrict__ be,
                           const float* __restrict__ hin, float* __restrict__ hout) {
    int tid = threadIdx.x;
    int wave = tid >> 6;
    int lane = tid & 63;
    int n = blockIdx.x * 4 + wave;
    if (n >= N_NODES) return;
    int e0 = offs[n], e1 = offs[n + 1];
    int side = lane >> 4;              // 0..3
    int cl = lane & 15;                // channel group
    int c = cl * 8;
    int h = cl >> 2;                   // head (H=4); ch c..c+7 all in head c/32 = cl/4
    float ald = (H == 4) ? al_dst[n * 4 + h] : al_dst[n];
    float acc[8] = {0.f, 0.f, 0.f, 0.f, 0.f, 0.f, 0.f, 0.f};
    float den = 0.f;

    auto fetchw = [&](int i, int& s, float& wv) {
        if (i < e1) {
            const float* rb = (const float*)(rec + (size_t)i * 4);
            s = __float_as_int(rb[9]);                       // meta.y = src
            float r = (H == 4) ? rb[SLOT * 4 + h] : rb[8];
            float al = ((H == 4) ? al_src[s * 4 + h] : al_src[s]) + ald + r;
            al = (al >= 0.f) ? al : 0.2f * al;
            wv = __expf(al);
        } else { s = 0; wv = 0.f; }
    };
    auto accum = [&](uint4 r, float wv) {
        union { uint4 u; __half2 h2[4]; } t2; t2.u = r;
        #pragma unroll
        for (int j = 0; j < 4; j++) {
            float2 f = __half22float2(t2.h2[j]);
            acc[j * 2]     += wv * f.x;
            acc[j * 2 + 1] += wv * f.y;
        }
        den += wv;
    };

    int i = e0 + side;                 // this side: i, i+4, i+8, ...
    int sA, sB; float wA, wB;
    fetchw(i, sA, wA);
    fetchw(i + 4, sB, wB);
    while (i < e1) {
        uint4 rA = *reinterpret_cast<const uint4*>(xp + (size_t)sA * HID + c);
        uint4 rB = *reinterpret_cast<const uint4*>(xp + (size_t)sB * HID + c);
        int sC, sD; float wC, wD;
        fetchw(i + 8, sC, wC);
        fetchw(i + 12, sD, wD);
        accum(rA, wA);
        accum(rB, wB);
        sA = sC; wA = wC; sB = sD; wB = wD;
        i += 8;
    }
    // combine 4 sides (lanes cl, cl+16, cl+32, cl+48 share channels)
    #pragma unroll
    for (int j = 0; j < 8; j++) {
        acc[j] += __shfl_xor(acc[j], 16, 64);
        acc[j] += __shfl_xor(acc[j], 32, 64);
    }
    den += __shfl_xor(den, 16, 64);
    den += __shfl_xor(den, 32, 64);

    float inv = 1.f / (den + 1e-16f);
    float v[8];
    const float4 bv0 = *reinterpret_cast<const float4*>(bias + c);
    const float4 bv1 = *reinterpret_cast<const float4*>(bias + c + 4);
    v[0] = acc[0] * inv + bv0.x; v[1] = acc[1] * inv + bv0.y;
    v[2] = acc[2] * inv + bv0.z; v[3] = acc[3] * inv + bv0.w;
    v[4] = acc[4] * inv + bv1.x; v[5] = acc[5] * inv + bv1.y;
    v[6] = acc[6] * inv + bv1.z; v[7] = acc[7] * inv + bv1.w;
    float s8 = v[0] + v[1] + v[2] + v[3] + v[4] + v[5] + v[6] + v[7];
    #pragma unroll
    for (int o = 8; o > 0; o >>= 1) s8 += __shfl_xor(s8, o, 64);
    float mean = s8 * (1.f / HID);
    float q8 = 0.f;
    float d[8];
    #pragma unroll
    for (int j = 0; j < 8; j++) { d[j] = v[j] - mean; q8 += d[j] * d[j]; }
    #pragma unroll
    for (int o = 8; o > 0; o >>= 1) q8 += __shfl_xor(q8, o, 64);
    float rstd = rsqrtf(q8 * (1.f / HID) + 1e-5f);
    if (side < 2) {                    // side0 -> ch c..c+3, side1 -> c+4..c+7
        int co = c + side * 4;
        int j0 = side * 4;
        const float4 gv  = *reinterpret_cast<const float4*>(g + co);
        const float4 bev = *reinterpret_cast<const float4*>(be + co);
        float y0 = d[j0]     * rstd * gv.x + bev.x;
        float y1 = d[j0 + 1] * rstd * gv.y + bev.y;
        float y2 = d[j0 + 2] * rstd * gv.z + bev.z;
        float y3 = d[j0 + 3] * rstd * gv.w + bev.w;
        y0 = (y0 > 0.f) ? y0 : (__expf(y0) - 1.f);
        y1 = (y1 > 0.f) ? y1 : (__expf(y1) - 1.f);
        y2 = (y2 > 0.f) ? y2 : (__expf(y2) - 1.f);
        y3 = (y3 > 0.f) ? y3 : (__expf(y3) - 1.f);
        const float4 rv = *reinterpret_cast<const float4*>(hin + (size_t)n * HID + co);
        *reinterpret_cast<float4*>(hout + (size_t)n * HID + co) =
            make_float4(y0 + rv.x, y1 + rv.y, y2 + rv.z, y3 + rv.w);
    }
}

// ---------------- gate MLP + graph bounds, tiled 16 nodes/block ----------------
__global__ void k_gate(const float* __restrict__ h, const float* __restrict__ gW1,
                       const float* __restrict__ gb1, const float* __restrict__ gW2,
                       const float* __restrict__ gb2, const int* __restrict__ batch,
                       float* __restrict__ gate, int* __restrict__ goff) {
    __shared__ float hs[16][HID];
    int tid = threadIdx.x;
    int base = blockIdx.x * 16;
    if (tid < 16) {                    // fused k_bounds
        int n = base + tid;
        int cur = batch[n];
        int prev = (n == 0) ? -1 : batch[n - 1];
        for (int gg = prev + 1; gg <= cur; gg++) goff[gg] = n;
        if (n == N_NODES - 1)
            for (int gg = cur + 1; gg <= NB; gg++) goff[gg] = N_NODES;
    }
    for (int idx = tid; idx < 16 * HID; idx += 256) {
        int nn = idx >> 7, k = idx & 127;
        hs[nn][k] = h[(size_t)(base + nn) * HID + k];
    }
    __syncthreads();
    int c = tid & 63;
    int wave = tid >> 6;
    float acc[4] = {0.f, 0.f, 0.f, 0.f};
    #pragma unroll 8
    for (int k = 0; k < HID; k++) {
        float wv = gW1[k * 64 + c];
        #pragma unroll
        for (int q = 0; q < 4; q++) acc[q] += hs[wave * 4 + q][k] * wv;
    }
    float b1 = gb1[c], w2 = gW2[c];
    float p[4];
    #pragma unroll
    for (int q = 0; q < 4; q++) p[q] = fmaxf(acc[q] + b1, 0.f) * w2;
    #pragma unroll
    for (int o = 32; o > 0; o >>= 1) {
        #pragma unroll
        for (int q = 0; q < 4; q++) p[q] += __shfl_xor(p[q], o, 64);
    }
    if (c == 0) {
        float b2 = gb2[0];
        #pragma unroll
        for (int q = 0; q < 4; q++) gate[base + wave * 4 + q] = p[q] + b2;
    }
}

// ---------------- fused: segment softmax over graphs + pooling + classifier head ----------------
__global__ void k_pool_head(const float* __restrict__ h, const float* __restrict__ gate,
                            const int* __restrict__ goff, const float* __restrict__ cW1,
                            const float* __restrict__ cb1, const float* __restrict__ cW2,
                            const float* __restrict__ cb2, float* __restrict__ out) {
    __shared__ float red[256];
    __shared__ float tr[64];
    int b = blockIdx.x;
    int t = threadIdx.x;
    int sG = goff[b], eG = goff[b + 1];
    float m = -__builtin_inff();
    for (int n = sG + t; n < eG; n += 256) m = fmaxf(m, gate[n]);
    red[t] = m;
    __syncthreads();
    for (int o = 128; o > 0; o >>= 1) { if (t < o) red[t] = fmaxf(red[t], red[t + o]); __syncthreads(); }
    m = red[0];
    __syncthreads();
    float dd = 0.f;
    for (int n = sG + t; n < eG; n += 256) dd += __expf(gate[n] - m);
    red[t] = dd;
    __syncthreads();
    for (int o = 128; o > 0; o >>= 1) { if (t < o) red[t] += red[t + o]; __syncthreads(); }
    float dinv = 1.f / (red[0] + 1e-16f);
    __syncthreads();
    int c = t & 127, pg = t >> 7;
    float acc = 0.f;
    for (int n = sG + pg; n < eG; n += 2)
        acc += __expf(gate[n] - m) * h[(size_t)n * HID + c];
    acc *= dinv;
    red[t] = acc;
    __syncthreads();
    float pc = 0.f;
    if (t < 128) pc = red[t] + red[t + 128];
    __syncthreads();
    if (t < 128) red[t] = pc;          // pooled row
    __syncthreads();
    if (t < 64) {
        float a = cb1[t];
        #pragma unroll 8
        for (int k = 0; k < HID; k++) a += red[k] * cW1[k * 64 + t];
        tr[t] = fmaxf(a, 0.f);
    }
    __syncthreads();
    if (t < NC) {
        float o = cb2[t];
        #pragma unroll
        for (int k = 0; k < 64; k++) o += tr[k] * cW2[k * NC + t];
        out[b * NC + t] = o;
    }
}

extern "C" void kernel_launch(void* const* d_in, const int* in_sizes, int n_in,
                              void* d_out, int out_size, void* d_ws, size_t ws_size,
                              hipStream_t stream) {
    (void)in_sizes; (void)n_in; (void)out_size; (void)ws_size;
    const float* x     = (const float*)d_in[0];
    const int*   ei    = (const int*)d_in[1];
    const float* ea    = (const float*)d_in[2];
    const int*   batch = (const int*)d_in[3];
    const float* pW    = (const float*)d_in[4];
    const float* pb    = (const float*)d_in[5];
    const float *W[3], *as_[3], *ad_[3], *ae_[3], *We[3], *bb[3], *gg[3], *be[3];
    for (int l = 0; l < 3; l++) {
        int base = 6 + 8 * l;
        W[l]   = (const float*)d_in[base + 0];
        as_[l] = (const float*)d_in[base + 1];
        ad_[l] = (const float*)d_in[base + 2];
        ae_[l] = (const float*)d_in[base + 3];
        We[l]  = (const float*)d_in[base + 4];
        bb[l]  = (const float*)d_in[base + 5];
        gg[l]  = (const float*)d_in[base + 6];
        be[l]  = (const float*)d_in[base + 7];
    }
    const float* gW1 = (const float*)d_in[30];
    const float* gb1 = (const float*)d_in[31];
    const float* gW2 = (const float*)d_in[32];
    const float* gb2 = (const float*)d_in[33];
    const float* cW1 = (const float*)d_in[34];
    const float* cb1 = (const float*)d_in[35];
    const float* cW2 = (const float*)d_in[36];
    const float* cb2 = (const float*)d_in[37];
    float* out = (float*)d_out;

    char* p = (char*)d_ws;
    auto take = [&](size_t bytes) -> char* {
        char* r = p;
        p += (bytes + 255) & ~(size_t)255;
        return r;
    };
    float*  h0      = (float*)take((size_t)N_NODES * HID * 4);
    float*  h1      = (float*)take((size_t)N_NODES * HID * 4);
    __half* xp      = (__half*)take((size_t)N_NODES * HID * 2);
    float*  al_src  = (float*)take((size_t)N_NODES * 4 * 4);
    float*  al_dst  = (float*)take((size_t)N_NODES * 4 * 4);
    float4* rec     = (float4*)take((size_t)N_EDGES * 64);
    int*    deg     = (int*)take((size_t)N_NODES * 4);
    int*    offs    = (int*)take((size_t)(N_NODES + 1) * 4);
    int*    rank    = (int*)take((size_t)N_EDGES * 4);
    int*    bsum    = (int*)take(256 * 4);
    int*    bpre    = (int*)take(256 * 4);
    float*  WeAe    = (float*)take(ED * 9 * 4);
    float*  gate    = (float*)take((size_t)N_NODES * 4);
    int*    goff    = (int*)take((NB + 1) * 4);
    f16*    Wtp     = (f16*)take(128 * 64 * 2);
    f16*    Wt0     = (f16*)take(128 * 128 * 2);
    f16*    Wt1     = (f16*)take(128 * 128 * 2);
    f16*    Wt2     = (f16*)take(128 * 128 * 2);
    f16*    Wt[3]   = {Wt0, Wt1, Wt2};

    const int* src = ei;
    const int* dst = ei + N_EDGES;

    k_setup<<<256, 256, 0, stream>>>(pW, W[0], W[1], W[2], We[0], ae_[0], We[1], ae_[1],
                                     We[2], ae_[2], deg, WeAe, Wtp, Wt0, Wt1, Wt2);
    k_gemm<64, 0><<<GEMM_BLOCKS, 256, 0, stream>>>(x, Wtp, pb, nullptr, nullptr,
                                                   h0, nullptr, nullptr, nullptr);
    k_deg<<<(N_EDGES + 255) / 256, 256, 0, stream>>>(dst, deg, rank);
    k_scanA<<<SCAN_BLOCKS, 256, 0, stream>>>(deg, bsum);
    k_scanB<<<1, 256, 0, stream>>>(bsum, bpre, offs);
    k_scanC<<<SCAN_BLOCKS, 256, 0, stream>>>(deg, bpre, offs);
    k_edge_build<<<(N_EDGES + 255) / 256, 256, 0, stream>>>(src, dst, rank, offs, ea, WeAe, rec);

    float* hc = h0;
    float* hn = h1;
    // layer 0
    k_gemm<128, 1><<<GEMM_BLOCKS, 256, 0, stream>>>(hc, Wt[0], nullptr, as_[0], ad_[0],
                                                    nullptr, xp, al_src, al_dst);
    k_node_agg<4, 0><<<(N_NODES + 3) / 4, 256, 0, stream>>>(offs, rec, al_src, al_dst, xp,
                                                            bb[0], gg[0], be[0], hc, hn);
    { float* t = hc; hc = hn; hn = t; }
    // layer 1
    k_gemm<128, 1><<<GEMM_BLOCKS, 256, 0, stream>>>(hc, Wt[1], nullptr, as_[1], ad_[1],
                                                    nullptr, xp, al_src, al_dst);
    k_node_agg<4, 1><<<(N_NODES + 3) / 4, 256, 0, stream>>>(offs, rec, al_src, al_dst, xp,
                                                            bb[1], gg[1], be[1], hc, hn);
    { float* t = hc; hc = hn; hn = t; }
    // layer 2
    k_gemm<128, 2><<<GEMM_BLOCKS, 256, 0, stream>>>(hc, Wt[2], nullptr, as_[2], ad_[2],
                                                    nullptr, xp, al_src, al_dst);
    k_node_agg<1, 0><<<(N_NODES + 3) / 4, 256, 0, stream>>>(offs, rec, al_src, al_dst, xp,
                                                            bb[2], gg[2], be[2], hc, hn);
    { float* t = hc; hc = hn; hn = t; }

    k_gate<<<N_NODES / 16, 256, 0, stream>>>(hc, gW1, gb1, gW2, gb2, batch, gate, goff);
    k_pool_head<<<NB, 256, 0, stream>>>(hc, gate, goff, cW1, cb1, cW2, cb2, out);
}

// Round 9
// 494.866 us; speedup vs baseline: 1.1705x; 1.1705x over previous
//
#include <hip/hip_runtime.h>
#include <hip/hip_fp16.h>
#include <math.h>

#define N_NODES 50000
#define N_EDGES 800000
#define NB      64
#define ND      64
#define ED      16
#define HID     128
#define NC      6
#define POOL_SPLIT 32
#define SCAN_BLOCKS ((N_NODES + 255) / 256)   // 196
#define GEMM_BLOCKS ((N_NODES + 63) / 64)     // 782

typedef _Float16 f16;
typedef f16  half8  __attribute__((ext_vector_type(8)));
typedef float floatx4 __attribute__((ext_vector_type(4)));

// ---------------- setup: zero deg+pooled + WeAe + fp16 weight transpose ----------------
__global__ void k_setup(const float* __restrict__ pW, const float* __restrict__ W0,
                        const float* __restrict__ W1, const float* __restrict__ W2,
                        const float* __restrict__ We0, const float* __restrict__ ae0,
                        const float* __restrict__ We1, const float* __restrict__ ae1,
                        const float* __restrict__ We2, const float* __restrict__ ae2,
                        int* __restrict__ deg, float* __restrict__ pooled,
                        float* __restrict__ WeAe,
                        f16* __restrict__ Wtp, f16* __restrict__ Wt0,
                        f16* __restrict__ Wt1, f16* __restrict__ Wt2) {
    int i = blockIdx.x * 256 + threadIdx.x;
    if (i < N_NODES) deg[i] = 0;
    if (i < NB * HID) pooled[i] = 0.f;
    if (i < 128 * 64) {
        int n = i / 64, k = i % 64;
        Wtp[i] = (f16)pW[k * 128 + n];
    }
    if (i < 128 * 128) {
        int n = i / 128, k = i % 128;
        Wt0[i] = (f16)W0[k * 128 + n];
        Wt1[i] = (f16)W1[k * 128 + n];
        Wt2[i] = (f16)W2[k * 128 + n];
    }
    if (i >= 60000 && i < 60144) {
        int t = i - 60000;
        if (t < 64) {
            int k = t >> 2, h = t & 3;
            float s = 0.f;
            for (int c = 0; c < 32; c++) s += We0[k * HID + h * 32 + c] * ae0[h * 32 + c];
            WeAe[k * 9 + h] = s;
        } else if (t < 128) {
            int tt = t - 64;
            int k = tt >> 2, h = tt & 3;
            float s = 0.f;
            for (int c = 0; c < 32; c++) s += We1[k * HID + h * 32 + c] * ae1[h * 32 + c];
            WeAe[k * 9 + 4 + h] = s;
        } else {
            int k = t - 128;
            float s = 0.f;
            for (int c = 0; c < HID; c++) s += We2[k * HID + c] * ae2[c];
            WeAe[k * 9 + 8] = s;
        }
    }
}

// ---------------- MFMA GEMM: out = act[M,K] @ W[K,128] ----------------
template <int K, int MODE>
__global__ __launch_bounds__(256) void k_gemm(
        const float* __restrict__ act, const f16* __restrict__ Wt,
        const float* __restrict__ bias, const float* __restrict__ as_,
        const float* __restrict__ ad_, float* __restrict__ hout,
        __half* __restrict__ xp, float* __restrict__ al_src,
        float* __restrict__ al_dst) {
    constexpr int KP = K + 8;
    __shared__ __align__(16) f16 A[64 * KP];
    __shared__ float part_s[4][64];
    __shared__ float part_d[4][64];
    int tid = threadIdx.x;
    int base = blockIdx.x * 64;

    constexpr int NV = 64 * K / 4 / 256;
    #pragma unroll
    for (int i = 0; i < NV; i++) {
        int v = tid + i * 256;
        int row = v / (K / 4);
        int k4 = v % (K / 4);
        float4 xv = make_float4(0.f, 0.f, 0.f, 0.f);
        if (base + row < N_NODES)
            xv = *(const float4*)(act + (size_t)(base + row) * K + k4 * 4);
        f16* dp = &A[row * KP + k4 * 4];
        dp[0] = (f16)xv.x; dp[1] = (f16)xv.y; dp[2] = (f16)xv.z; dp[3] = (f16)xv.w;
    }
    __syncthreads();

    int w = tid >> 6, l = tid & 63;
    int lm = l & 15, q = l >> 4;
    floatx4 acc[4][2];
    #pragma unroll
    for (int mt = 0; mt < 4; mt++)
        #pragma unroll
        for (int j = 0; j < 2; j++)
            acc[mt][j] = (floatx4){0.f, 0.f, 0.f, 0.f};

    #pragma unroll
    for (int kt = 0; kt < K / 32; kt++) {
        int ko = kt * 32 + q * 8;
        half8 b0 = *(const half8*)(Wt + (size_t)(w * 32 + lm) * K + ko);
        half8 b1 = *(const half8*)(Wt + (size_t)(w * 32 + 16 + lm) * K + ko);
        #pragma unroll
        for (int mt = 0; mt < 4; mt++) {
            half8 a = *(const half8*)(&A[(mt * 16 + lm) * KP + ko]);
            acc[mt][0] = __builtin_amdgcn_mfma_f32_16x16x32_f16(a, b0, acc[mt][0], 0, 0, 0);
            acc[mt][1] = __builtin_amdgcn_mfma_f32_16x16x32_f16(a, b1, acc[mt][1], 0, 0, 0);
        }
    }

    if (MODE == 0) {
        float b0 = bias[w * 32 + lm];
        float b1 = bias[w * 32 + 16 + lm];
        #pragma unroll
        for (int mt = 0; mt < 4; mt++)
            #pragma unroll
            for (int r = 0; r < 4; r++) {
                int row = mt * 16 + q * 4 + r;
                if (base + row < N_NODES) {
                    hout[(size_t)(base + row) * HID + w * 32 + lm]      = fmaxf(acc[mt][0][r] + b0, 0.f);
                    hout[(size_t)(base + row) * HID + w * 32 + 16 + lm] = fmaxf(acc[mt][1][r] + b1, 0.f);
                }
            }
    } else {
        float a0 = as_[w * 32 + lm], a1 = as_[w * 32 + 16 + lm];
        float e0 = ad_[w * 32 + lm], e1 = ad_[w * 32 + 16 + lm];
        float ps[4][4], pd[4][4];
        #pragma unroll
        for (int mt = 0; mt < 4; mt++)
            #pragma unroll
            for (int r = 0; r < 4; r++) {
                ps[mt][r] = acc[mt][0][r] * a0 + acc[mt][1][r] * a1;
                pd[mt][r] = acc[mt][0][r] * e0 + acc[mt][1][r] * e1;
            }
        #pragma unroll
        for (int off = 1; off < 16; off <<= 1)
            #pragma unroll
            for (int mt = 0; mt < 4; mt++)
                #pragma unroll
                for (int r = 0; r < 4; r++) {
                    ps[mt][r] += __shfl_xor(ps[mt][r], off, 64);
                    pd[mt][r] += __shfl_xor(pd[mt][r], off, 64);
                }
        if (MODE == 1) {
            if (lm == 0)
                #pragma unroll
                for (int mt = 0; mt < 4; mt++)
                    #pragma unroll
                    for (int r = 0; r < 4; r++) {
                        int n = base + mt * 16 + q * 4 + r;
                        if (n < N_NODES) {
                            al_src[n * 4 + w] = ps[mt][r];
                            al_dst[n * 4 + w] = pd[mt][r];
                        }
                    }
        } else {
            if (lm == 0)
                #pragma unroll
                for (int mt = 0; mt < 4; mt++)
                    #pragma unroll
                    for (int r = 0; r < 4; r++) {
                        part_s[w][mt * 16 + q * 4 + r] = ps[mt][r];
                        part_d[w][mt * 16 + q * 4 + r] = pd[mt][r];
                    }
        }
        __syncthreads();
        #pragma unroll
        for (int mt = 0; mt < 4; mt++)
            #pragma unroll
            for (int r = 0; r < 4; r++) {
                int row = mt * 16 + q * 4 + r;
                A[row * KP + w * 32 + lm]      = (f16)acc[mt][0][r];
                A[row * KP + w * 32 + 16 + lm] = (f16)acc[mt][1][r];
            }
        if (MODE == 2 && tid < 64) {
            int n = base + tid;
            if (n < N_NODES) {
                al_src[n] = part_s[0][tid] + part_s[1][tid] + part_s[2][tid] + part_s[3][tid];
                al_dst[n] = part_d[0][tid] + part_d[1][tid] + part_d[2][tid] + part_d[3][tid];
            }
        }
        __syncthreads();
        #pragma unroll
        for (int i = 0; i < 4; i++) {
            int v = tid + i * 256;
            int row = v >> 4, c8 = v & 15;
            if (base + row < N_NODES) {
                float4 hv = *(const float4*)(&A[row * KP + c8 * 8]);
                *reinterpret_cast<float4*>(reinterpret_cast<char*>(xp) +
                    ((size_t)(base + row) * HID + c8 * 8) * 2) = hv;
            }
        }
    }
}

// ---------------- degree + per-edge rank ----------------
__global__ void k_deg(const int* __restrict__ dst, int* __restrict__ deg,
                      int* __restrict__ rank) {
    int e = blockIdx.x * blockDim.x + threadIdx.x;
    if (e < N_EDGES) rank[e] = atomicAdd(&deg[dst[e]], 1);
}

__global__ void k_scanA(const int* __restrict__ deg, int* __restrict__ bsum) {
    __shared__ int wsu[4];
    int t = threadIdx.x;
    int i = blockIdx.x * 256 + t;
    int d = (i < N_NODES) ? deg[i] : 0;
    int v = d;
    #pragma unroll
    for (int o = 32; o > 0; o >>= 1) v += __shfl_xor(v, o, 64);
    if ((t & 63) == 0) wsu[t >> 6] = v;
    __syncthreads();
    if (t == 0) bsum[blockIdx.x] = wsu[0] + wsu[1] + wsu[2] + wsu[3];
}

__global__ void k_scanB(const int* __restrict__ bsum, int* __restrict__ bpre,
                        int* __restrict__ offs) {
    __shared__ int sc[256];
    int t = threadIdx.x;
    int d = (t < SCAN_BLOCKS) ? bsum[t] : 0;
    sc[t] = d;
    __syncthreads();
    for (int o = 1; o < 256; o <<= 1) {
        int v = (t >= o) ? sc[t - o] : 0;
        __syncthreads();
        sc[t] += v;
        __syncthreads();
    }
    if (t < SCAN_BLOCKS) bpre[t] = sc[t] - d;
    if (t == 0) offs[N_NODES] = N_EDGES;
}

__global__ void k_scanC(const int* __restrict__ deg, const int* __restrict__ bpre,
                        int* __restrict__ offs) {
    __shared__ int sc[256];
    int t = threadIdx.x;
    int i = blockIdx.x * 256 + t;
    int d = (i < N_NODES) ? deg[i] : 0;
    sc[t] = d;
    __syncthreads();
    for (int o = 1; o < 256; o <<= 1) {
        int v = (t >= o) ? sc[t - o] : 0;
        __syncthreads();
        sc[t] += v;
        __syncthreads();
    }
    if (i < N_NODES) offs[i] = bpre[blockIdx.x] + sc[t] - d;
}

// ---------------- build packed CSR records (atomic-free, full-line scatter) ----------------
__global__ void k_edge_build(const int* __restrict__ src, const int* __restrict__ dst,
                             const int* __restrict__ rank, const int* __restrict__ offs,
                             const float* __restrict__ ea, const float* __restrict__ WeAe,
                             float4* __restrict__ rec) {
    __shared__ float w[ED * 9];
    __shared__ float4 rs[256][4];
    __shared__ int rp[256];
    int tid = threadIdx.x;
    if (tid < ED * 9) w[tid] = WeAe[tid];
    __syncthreads();
    int e = blockIdx.x * 256 + tid;
    if (e < N_EDGES) {
        float ev[ED];
        const float4* ep4 = reinterpret_cast<const float4*>(ea + (size_t)e * ED);
        #pragma unroll
        for (int q = 0; q < 4; q++) {
            float4 v = ep4[q];
            ev[q * 4 + 0] = v.x; ev[q * 4 + 1] = v.y;
            ev[q * 4 + 2] = v.z; ev[q * 4 + 3] = v.w;
        }
        float r[9];
        #pragma unroll
        for (int j = 0; j < 9; j++) r[j] = 0.f;
        #pragma unroll
        for (int k = 0; k < ED; k++) {
            float evk = ev[k];
            #pragma unroll
            for (int j = 0; j < 9; j++) r[j] += evk * w[k * 9 + j];
        }
        int d = dst[e], s = src[e];
        rp[tid] = offs[d] + rank[e];
        rs[tid][0] = make_float4(r[0], r[1], r[2], r[3]);
        rs[tid][1] = make_float4(r[4], r[5], r[6], r[7]);
        rs[tid][2] = make_float4(r[8], __int_as_float(s), __int_as_float(d), 0.f);
        rs[tid][3] = make_float4(0.f, 0.f, 0.f, 0.f);
    } else {
        rp[tid] = -1;
    }
    __syncthreads();
    int g0 = tid >> 2, q = tid & 3;
    #pragma unroll
    for (int rr = 0; rr < 4; rr++) {
        int g = rr * 64 + g0;
        int p = rp[g];
        if (p >= 0) rec[(size_t)p * 4 + q] = rs[g][q];
    }
}

// ---------------- fused agg: on-the-fly edge weights + gather + softmax-norm + LN + ELU + res ----
template <int H, int SLOT>
__global__ void k_node_agg(const int* __restrict__ offs, const float4* __restrict__ rec,
                           const float* __restrict__ al_src, const float* __restrict__ al_dst,
                           const __half* __restrict__ xp, const float* __restrict__ bias,
                           const float* __restrict__ g, const float* __restrict__ be,
                           const float* __restrict__ hin, float* __restrict__ hout) {
    int tid = threadIdx.x;
    int wave = tid >> 6;
    int lane = tid & 63;
    int n = blockIdx.x * 4 + wave;
    if (n >= N_NODES) return;
    int e0 = offs[n], e1 = offs[n + 1];
    int side = lane >> 4;              // 0..3
    int cl = lane & 15;
    int c = cl * 8;
    int h = cl >> 2;
    float ald = (H == 4) ? al_dst[n * 4 + h] : al_dst[n];
    float acc[8] = {0.f, 0.f, 0.f, 0.f, 0.f, 0.f, 0.f, 0.f};
    float den = 0.f;

    auto fetchw = [&](int i, int& s, float& wv) {
        if (i < e1) {
            const float* rb = (const float*)(rec + (size_t)i * 4);
            s = __float_as_int(rb[9]);
            float r = (H == 4) ? rb[SLOT * 4 + h] : rb[8];
            float al = ((H == 4) ? al_src[s * 4 + h] : al_src[s]) + ald + r;
            al = (al >= 0.f) ? al : 0.2f * al;
            wv = __expf(al);
        } else { s = 0; wv = 0.f; }
    };
    auto accum = [&](uint4 r, float wv) {
        union { uint4 u; __half2 h2[4]; } t2; t2.u = r;
        #pragma unroll
        for (int j = 0; j < 4; j++) {
            float2 f = __half22float2(t2.h2[j]);
            acc[j * 2]     += wv * f.x;
            acc[j * 2 + 1] += wv * f.y;
        }
        den += wv;
    };

    int i = e0 + side;
    int sA, sB; float wA, wB;
    fetchw(i, sA, wA);
    fetchw(i + 4, sB, wB);
    while (i < e1) {
        uint4 rA = *reinterpret_cast<const uint4*>(xp + (size_t)sA * HID + c);
        uint4 rB = *reinterpret_cast<const uint4*>(xp + (size_t)sB * HID + c);
        int sC, sD; float wC, wD;
        fetchw(i + 8, sC, wC);
        fetchw(i + 12, sD, wD);
        accum(rA, wA);
        accum(rB, wB);
        sA = sC; wA = wC; sB = sD; wB = wD;
        i += 8;
    }
    #pragma unroll
    for (int j = 0; j < 8; j++) {
        acc[j] += __shfl_xor(acc[j], 16, 64);
        acc[j] += __shfl_xor(acc[j], 32, 64);
    }
    den += __shfl_xor(den, 16, 64);
    den += __shfl_xor(den, 32, 64);

    float inv = 1.f / (den + 1e-16f);
    float v[8];
    const float4 bv0 = *reinterpret_cast<const float4*>(bias + c);
    const float4 bv1 = *reinterpret_cast<const float4*>(bias + c + 4);
    v[0] = acc[0] * inv + bv0.x; v[1] = acc[1] * inv + bv0.y;
    v[2] = acc[2] * inv + bv0.z; v[3] = acc[3] * inv + bv0.w;
    v[4] = acc[4] * inv + bv1.x; v[5] = acc[5] * inv + bv1.y;
    v[6] = acc[6] * inv + bv1.z; v[7] = acc[7] * inv + bv1.w;
    float s8 = v[0] + v[1] + v[2] + v[3] + v[4] + v[5] + v[6] + v[7];
    #pragma unroll
    for (int o = 8; o > 0; o >>= 1) s8 += __shfl_xor(s8, o, 64);
    float mean = s8 * (1.f / HID);
    float q8 = 0.f;
    float d[8];
    #pragma unroll
    for (int j = 0; j < 8; j++) { d[j] = v[j] - mean; q8 += d[j] * d[j]; }
    #pragma unroll
    for (int o = 8; o > 0; o >>= 1) q8 += __shfl_xor(q8, o, 64);
    float rstd = rsqrtf(q8 * (1.f / HID) + 1e-5f);
    if (side < 2) {
        int co = c + side * 4;
        int j0 = side * 4;
        const float4 gv  = *reinterpret_cast<const float4*>(g + co);
        const float4 bev = *reinterpret_cast<const float4*>(be + co);
        float y0 = d[j0]     * rstd * gv.x + bev.x;
        float y1 = d[j0 + 1] * rstd * gv.y + bev.y;
        float y2 = d[j0 + 2] * rstd * gv.z + bev.z;
        float y3 = d[j0 + 3] * rstd * gv.w + bev.w;
        y0 = (y0 > 0.f) ? y0 : (__expf(y0) - 1.f);
        y1 = (y1 > 0.f) ? y1 : (__expf(y1) - 1.f);
        y2 = (y2 > 0.f) ? y2 : (__expf(y2) - 1.f);
        y3 = (y3 > 0.f) ? y3 : (__expf(y3) - 1.f);
        const float4 rv = *reinterpret_cast<const float4*>(hin + (size_t)n * HID + co);
        *reinterpret_cast<float4*>(hout + (size_t)n * HID + co) =
            make_float4(y0 + rv.x, y1 + rv.y, y2 + rv.z, y3 + rv.w);
    }
}

// ---------------- gate MLP + graph bounds, tiled 16 nodes/block ----------------
__global__ void k_gate(const float* __restrict__ h, const float* __restrict__ gW1,
                       const float* __restrict__ gb1, const float* __restrict__ gW2,
                       const float* __restrict__ gb2, const int* __restrict__ batch,
                       float* __restrict__ gate, int* __restrict__ goff) {
    __shared__ float hs[16][HID];
    int tid = threadIdx.x;
    int base = blockIdx.x * 16;
    if (tid < 16) {
        int n = base + tid;
        int cur = batch[n];
        int prev = (n == 0) ? -1 : batch[n - 1];
        for (int gg = prev + 1; gg <= cur; gg++) goff[gg] = n;
        if (n == N_NODES - 1)
            for (int gg = cur + 1; gg <= NB; gg++) goff[gg] = N_NODES;
    }
    for (int idx = tid; idx < 16 * HID; idx += 256) {
        int nn = idx >> 7, k = idx & 127;
        hs[nn][k] = h[(size_t)(base + nn) * HID + k];
    }
    __syncthreads();
    int c = tid & 63;
    int wave = tid >> 6;
    float acc[4] = {0.f, 0.f, 0.f, 0.f};
    #pragma unroll 8
    for (int k = 0; k < HID; k++) {
        float wv = gW1[k * 64 + c];
        #pragma unroll
        for (int q = 0; q < 4; q++) acc[q] += hs[wave * 4 + q][k] * wv;
    }
    float b1 = gb1[c], w2 = gW2[c];
    float p[4];
    #pragma unroll
    for (int q = 0; q < 4; q++) p[q] = fmaxf(acc[q] + b1, 0.f) * w2;
    #pragma unroll
    for (int o = 32; o > 0; o >>= 1) {
        #pragma unroll
        for (int q = 0; q < 4; q++) p[q] += __shfl_xor(p[q], o, 64);
    }
    if (c == 0) {
        float b2 = gb2[0];
        #pragma unroll
        for (int q = 0; q < 4; q++) gate[base + wave * 4 + q] = p[q] + b2;
    }
}

__global__ void k_gmaxden(const float* __restrict__ gate, const int* __restrict__ goff,
                          float* __restrict__ gmax, float* __restrict__ gden) {
    int b = blockIdx.x;
    int t = threadIdx.x;
    __shared__ float red[256];
    int s = goff[b], e = goff[b + 1];
    float m = -__builtin_inff();
    for (int n = s + t; n < e; n += 256) m = fmaxf(m, gate[n]);
    red[t] = m;
    __syncthreads();
    for (int o = 128; o > 0; o >>= 1) { if (t < o) red[t] = fmaxf(red[t], red[t + o]); __syncthreads(); }
    m = red[0];
    __syncthreads();
    float d = 0.f;
    for (int n = s + t; n < e; n += 256) d += __expf(gate[n] - m);
    red[t] = d;
    __syncthreads();
    for (int o = 128; o > 0; o >>= 1) { if (t < o) red[t] += red[t + o]; __syncthreads(); }
    if (t == 0) { gmax[b] = m; gden[b] = red[0]; }
}

__global__ void k_pool(const float* __restrict__ h, const float* __restrict__ gate,
                       const float* __restrict__ gmax, const float* __restrict__ gden,
                       const int* __restrict__ goff, float* __restrict__ pooled) {
    int b = blockIdx.x;
    int part = blockIdx.y;
    int c = threadIdx.x;
    int s = goff[b], e = goff[b + 1];
    float m = gmax[b];
    float dinv = 1.f / (gden[b] + 1e-16f);
    float acc = 0.f;
    for (int n = s + part; n < e; n += POOL_SPLIT) {
        float att = __expf(gate[n] - m) * dinv;
        acc += att * h[(size_t)n * HID + c];
    }
    atomicAdd(&pooled[b * HID + c], acc);
}

__global__ void k_head(const float* __restrict__ pooled, const float* __restrict__ cW1,
                       const float* __restrict__ cb1, const float* __restrict__ cW2,
                       const float* __restrict__ cb2, float* __restrict__ out) {
    int b = blockIdx.x;
    int t = threadIdx.x;
    __shared__ float pr[HID];
    __shared__ float tr[64];
    pr[t] = pooled[b * HID + t];
    pr[t + 64] = pooled[b * HID + t + 64];
    __syncthreads();
    float a = cb1[t];
    #pragma unroll 8
    for (int k = 0; k < HID; k++) a += pr[k] * cW1[k * 64 + t];
    tr[t] = fmaxf(a, 0.f);
    __syncthreads();
    if (t < NC) {
        float o = cb2[t];
        #pragma unroll
        for (int k = 0; k < 64; k++) o += tr[k] * cW2[k * NC + t];
        out[b * NC + t] = o;
    }
}

extern "C" void kernel_launch(void* const* d_in, const int* in_sizes, int n_in,
                              void* d_out, int out_size, void* d_ws, size_t ws_size,
                              hipStream_t stream) {
    (void)in_sizes; (void)n_in; (void)out_size; (void)ws_size;
    const float* x     = (const float*)d_in[0];
    const int*   ei    = (const int*)d_in[1];
    const float* ea    = (const float*)d_in[2];
    const int*   batch = (const int*)d_in[3];
    const float* pW    = (const float*)d_in[4];
    const float* pb    = (const float*)d_in[5];
    const float *W[3], *as_[3], *ad_[3], *ae_[3], *We[3], *bb[3], *gg[3], *be[3];
    for (int l = 0; l < 3; l++) {
        int base = 6 + 8 * l;
        W[l]   = (const float*)d_in[base + 0];
        as_[l] = (const float*)d_in[base + 1];
        ad_[l] = (const float*)d_in[base + 2];
        ae_[l] = (const float*)d_in[base + 3];
        We[l]  = (const float*)d_in[base + 4];
        bb[l]  = (const float*)d_in[base + 5];
        gg[l]  = (const float*)d_in[base + 6];
        be[l]  = (const float*)d_in[base + 7];
    }
    const float* gW1 = (const float*)d_in[30];
    const float* gb1 = (const float*)d_in[31];
    const float* gW2 = (const float*)d_in[32];
    const float* gb2 = (const float*)d_in[33];
    const float* cW1 = (const float*)d_in[34];
    const float* cb1 = (const float*)d_in[35];
    const float* cW2 = (const float*)d_in[36];
    const float* cb2 = (const float*)d_in[37];
    float* out = (float*)d_out;

    char* p = (char*)d_ws;
    auto take = [&](size_t bytes) -> char* {
        char* r = p;
        p += (bytes + 255) & ~(size_t)255;
        return r;
    };
    float*  h0      = (float*)take((size_t)N_NODES * HID * 4);
    float*  h1      = (float*)take((size_t)N_NODES * HID * 4);
    __half* xp      = (__half*)take((size_t)N_NODES * HID * 2);
    float*  al_src  = (float*)take((size_t)N_NODES * 4 * 4);
    float*  al_dst  = (float*)take((size_t)N_NODES * 4 * 4);
    float4* rec     = (float4*)take((size_t)N_EDGES * 64);
    int*    deg     = (int*)take((size_t)N_NODES * 4);
    int*    offs    = (int*)take((size_t)(N_NODES + 1) * 4);
    int*    rank    = (int*)take((size_t)N_EDGES * 4);
    int*    bsum    = (int*)take(256 * 4);
    int*    bpre    = (int*)take(256 * 4);
    float*  WeAe    = (float*)take(ED * 9 * 4);
    float*  gate    = (float*)take((size_t)N_NODES * 4);
    float*  gmax    = (float*)take(NB * 4);
    float*  gden    = (float*)take(NB * 4);
    int*    goff    = (int*)take((NB + 1) * 4);
    float*  pooled  = (float*)take(NB * HID * 4);
    f16*    Wtp     = (f16*)take(128 * 64 * 2);
    f16*    Wt0     = (f16*)take(128 * 128 * 2);
    f16*    Wt1     = (f16*)take(128 * 128 * 2);
    f16*    Wt2     = (f16*)take(128 * 128 * 2);
    f16*    Wt[3]   = {Wt0, Wt1, Wt2};

    const int* src = ei;
    const int* dst = ei + N_EDGES;

    k_setup<<<256, 256, 0, stream>>>(pW, W[0], W[1], W[2], We[0], ae_[0], We[1], ae_[1],
                                     We[2], ae_[2], deg, pooled, WeAe, Wtp, Wt0, Wt1, Wt2);
    k_gemm<64, 0><<<GEMM_BLOCKS, 256, 0, stream>>>(x, Wtp, pb, nullptr, nullptr,
                                                   h0, nullptr, nullptr, nullptr);
    k_deg<<<(N_EDGES + 255) / 256, 256, 0, stream>>>(dst, deg, rank);
    k_scanA<<<SCAN_BLOCKS, 256, 0, stream>>>(deg, bsum);
    k_scanB<<<1, 256, 0, stream>>>(bsum, bpre, offs);
    k_scanC<<<SCAN_BLOCKS, 256, 0, stream>>>(deg, bpre, offs);
    k_edge_build<<<(N_EDGES + 255) / 256, 256, 0, stream>>>(src, dst, rank, offs, ea, WeAe, rec);

    float* hc = h0;
    float* hn = h1;
    // layer 0
    k_gemm<128, 1><<<GEMM_BLOCKS, 256, 0, stream>>>(hc, Wt[0], nullptr, as_[0], ad_[0],
                                                    nullptr, xp, al_src, al_dst);
    k_node_agg<4, 0><<<(N_NODES + 3) / 4, 256, 0, stream>>>(offs, rec, al_src, al_dst, xp,
                                                            bb[0], gg[0], be[0], hc, hn);
    { float* t = hc; hc = hn; hn = t; }
    // layer 1
    k_gemm<128, 1><<<GEMM_BLOCKS, 256, 0, stream>>>(hc, Wt[1], nullptr, as_[1], ad_[1],
                                                    nullptr, xp, al_src, al_dst);
    k_node_agg<4, 1><<<(N_NODES + 3) / 4, 256, 0, stream>>>(offs, rec, al_src, al_dst, xp,
                                                            bb[1], gg[1], be[1], hc, hn);
    { float* t = hc; hc = hn; hn = t; }
    // layer 2
    k_gemm<128, 2><<<GEMM_BLOCKS, 256, 0, stream>>>(hc, Wt[2], nullptr, as_[2], ad_[2],
                                                    nullptr, xp, al_src, al_dst);
    k_node_agg<1, 0><<<(N_NODES + 3) / 4, 256, 0, stream>>>(offs, rec, al_src, al_dst, xp,
                                                            bb[2], gg[2], be[2], hc, hn);
    { float* t = hc; hc = hn; hn = t; }

    k_gate<<<N_NODES / 16, 256, 0, stream>>>(hc, gW1, gb1, gW2, gb2, batch, gate, goff);
    k_gmaxden<<<NB, 256, 0, stream>>>(gate, goff, gmax, gden);
    k_pool<<<dim3(NB, POOL_SPLIT), HID, 0, stream>>>(hc, gate, gmax, gden, goff, pooled);
    k_head<<<NB, 64, 0, stream>>>(pooled, cW1, cb1, cW2, cb2, out);
}

// Round 10
// 483.988 us; speedup vs baseline: 1.1968x; 1.0225x over previous
//
#include <hip/hip_runtime.h>
#include <hip/hip_fp16.h>
#include <math.h>

#define N_NODES 50000
#define N_EDGES 800000
#define NB      64
#define ND      64
#define ED      16
#define HID     128
#define NC      6
#define POOL_SPLIT 32
#define SCAN_BLOCKS ((N_NODES + 255) / 256)   // 196
#define GEMM_BLOCKS ((N_NODES + 63) / 64)     // 782
#define DEG_BLOCKS  ((N_EDGES + 255) / 256)   // 3125

typedef _Float16 f16;
typedef f16  half8  __attribute__((ext_vector_type(8)));
typedef float floatx4 __attribute__((ext_vector_type(4)));

// ---------------- setup: zero deg+pooled + WeAe + fp16 weight transpose ----------------
__global__ void k_setup(const float* __restrict__ pW, const float* __restrict__ W0,
                        const float* __restrict__ W1, const float* __restrict__ W2,
                        const float* __restrict__ We0, const float* __restrict__ ae0,
                        const float* __restrict__ We1, const float* __restrict__ ae1,
                        const float* __restrict__ We2, const float* __restrict__ ae2,
                        int* __restrict__ deg, float* __restrict__ pooled,
                        float* __restrict__ WeAe,
                        f16* __restrict__ Wtp, f16* __restrict__ Wt0,
                        f16* __restrict__ Wt1, f16* __restrict__ Wt2) {
    int i = blockIdx.x * 256 + threadIdx.x;
    if (i < N_NODES) deg[i] = 0;
    if (i < NB * HID) pooled[i] = 0.f;
    if (i < 128 * 64) {
        int n = i / 64, k = i % 64;
        Wtp[i] = (f16)pW[k * 128 + n];
    }
    if (i < 128 * 128) {
        int n = i / 128, k = i % 128;
        Wt0[i] = (f16)W0[k * 128 + n];
        Wt1[i] = (f16)W1[k * 128 + n];
        Wt2[i] = (f16)W2[k * 128 + n];
    }
    if (i >= 60000 && i < 60144) {
        int t = i - 60000;
        if (t < 64) {
            int k = t >> 2, h = t & 3;
            float s = 0.f;
            for (int c = 0; c < 32; c++) s += We0[k * HID + h * 32 + c] * ae0[h * 32 + c];
            WeAe[k * 9 + h] = s;
        } else if (t < 128) {
            int tt = t - 64;
            int k = tt >> 2, h = tt & 3;
            float s = 0.f;
            for (int c = 0; c < 32; c++) s += We1[k * HID + h * 32 + c] * ae1[h * 32 + c];
            WeAe[k * 9 + 4 + h] = s;
        } else {
            int k = t - 128;
            float s = 0.f;
            for (int c = 0; c < HID; c++) s += We2[k * HID + c] * ae2[c];
            WeAe[k * 9 + 8] = s;
        }
    }
}

// ---------------- MFMA GEMM body: out = act[M,K] @ W[K,128] ----------------
// MODE 0: h(fp16) = relu(out + bias)
// MODE 1: xp fp16 + al_src/al_dst per head (H=4)
// MODE 2: xp fp16 + al_src/al_dst (H=1)
template <int K, int MODE, typename AT>
__device__ __forceinline__ void gemm_body(
        const AT* __restrict__ act, const f16* __restrict__ Wt,
        const float* __restrict__ bias, const float* __restrict__ as_,
        const float* __restrict__ ad_, __half* __restrict__ hout,
        __half* __restrict__ xp, float* __restrict__ al_src,
        float* __restrict__ al_dst, int blk) {
    constexpr int KP = K + 8;           // input stage stride (halves)
    constexpr int OP = HID + 8;         // output stage stride (136)
    __shared__ __align__(16) f16 A[64 * OP];
    __shared__ float part_s[4][64];
    __shared__ float part_d[4][64];
    int tid = threadIdx.x;
    int base = blk * 64;

    if constexpr (sizeof(AT) == 4) {    // fp32 input, cvt to fp16
        constexpr int NV = 64 * (K / 4) / 256;
        #pragma unroll
        for (int i = 0; i < NV; i++) {
            int v = tid + i * 256;
            int row = v / (K / 4), k4 = v % (K / 4);
            float4 xv = make_float4(0.f, 0.f, 0.f, 0.f);
            if (base + row < N_NODES)
                xv = *(const float4*)((const float*)act + (size_t)(base + row) * K + k4 * 4);
            f16* dp = &A[row * KP + k4 * 4];
            dp[0] = (f16)xv.x; dp[1] = (f16)xv.y; dp[2] = (f16)xv.z; dp[3] = (f16)xv.w;
        }
    } else {                            // fp16 input, raw copy
        constexpr int NV = 64 * (K / 8) / 256;
        #pragma unroll
        for (int i = 0; i < NV; i++) {
            int v = tid + i * 256;
            int row = v / (K / 8), k8 = v % (K / 8);
            uint4 xv = make_uint4(0, 0, 0, 0);
            if (base + row < N_NODES)
                xv = *(const uint4*)((const __half*)act + (size_t)(base + row) * K + k8 * 8);
            *(uint4*)(&A[row * KP + k8 * 8]) = xv;
        }
    }
    __syncthreads();

    int w = tid >> 6, l = tid & 63;
    int lm = l & 15, q = l >> 4;
    floatx4 acc[4][2];
    #pragma unroll
    for (int mt = 0; mt < 4; mt++)
        #pragma unroll
        for (int j = 0; j < 2; j++)
            acc[mt][j] = (floatx4){0.f, 0.f, 0.f, 0.f};

    #pragma unroll
    for (int kt = 0; kt < K / 32; kt++) {
        int ko = kt * 32 + q * 8;
        half8 b0 = *(const half8*)(Wt + (size_t)(w * 32 + lm) * K + ko);
        half8 b1 = *(const half8*)(Wt + (size_t)(w * 32 + 16 + lm) * K + ko);
        #pragma unroll
        for (int mt = 0; mt < 4; mt++) {
            half8 a = *(const half8*)(&A[(mt * 16 + lm) * KP + ko]);
            acc[mt][0] = __builtin_amdgcn_mfma_f32_16x16x32_f16(a, b0, acc[mt][0], 0, 0, 0);
            acc[mt][1] = __builtin_amdgcn_mfma_f32_16x16x32_f16(a, b1, acc[mt][1], 0, 0, 0);
        }
    }

    if (MODE == 0) {
        float b0 = bias[w * 32 + lm];
        float b1 = bias[w * 32 + 16 + lm];
        __syncthreads();               // all A reads done
        #pragma unroll
        for (int mt = 0; mt < 4; mt++)
            #pragma unroll
            for (int r = 0; r < 4; r++) {
                int row = mt * 16 + q * 4 + r;
                A[row * OP + w * 32 + lm]      = (f16)fmaxf(acc[mt][0][r] + b0, 0.f);
                A[row * OP + w * 32 + 16 + lm] = (f16)fmaxf(acc[mt][1][r] + b1, 0.f);
            }
        __syncthreads();
        #pragma unroll
        for (int i = 0; i < 4; i++) {
            int v = tid + i * 256;
            int row = v >> 4, c8 = v & 15;
            if (base + row < N_NODES) {
                float4 hv = *(const float4*)(&A[row * OP + c8 * 8]);
                *reinterpret_cast<float4*>(reinterpret_cast<char*>(hout) +
                    ((size_t)(base + row) * HID + c8 * 8) * 2) = hv;
            }
        }
    } else {
        float a0 = as_[w * 32 + lm], a1 = as_[w * 32 + 16 + lm];
        float e0 = ad_[w * 32 + lm], e1 = ad_[w * 32 + 16 + lm];
        float ps[4][4], pd[4][4];
        #pragma unroll
        for (int mt = 0; mt < 4; mt++)
            #pragma unroll
            for (int r = 0; r < 4; r++) {
                ps[mt][r] = acc[mt][0][r] * a0 + acc[mt][1][r] * a1;
                pd[mt][r] = acc[mt][0][r] * e0 + acc[mt][1][r] * e1;
            }
        #pragma unroll
        for (int off = 1; off < 16; off <<= 1)
            #pragma unroll
            for (int mt = 0; mt < 4; mt++)
                #pragma unroll
                for (int r = 0; r < 4; r++) {
                    ps[mt][r] += __shfl_xor(ps[mt][r], off, 64);
                    pd[mt][r] += __shfl_xor(pd[mt][r], off, 64);
                }
        if (MODE == 1) {
            if (lm == 0)
                #pragma unroll
                for (int mt = 0; mt < 4; mt++)
                    #pragma unroll
                    for (int r = 0; r < 4; r++) {
                        int n = base + mt * 16 + q * 4 + r;
                        if (n < N_NODES) {
                            al_src[n * 4 + w] = ps[mt][r];
                            al_dst[n * 4 + w] = pd[mt][r];
                        }
                    }
        } else {
            if (lm == 0)
                #pragma unroll
                for (int mt = 0; mt < 4; mt++)
                    #pragma unroll
                    for (int r = 0; r < 4; r++) {
                        part_s[w][mt * 16 + q * 4 + r] = ps[mt][r];
                        part_d[w][mt * 16 + q * 4 + r] = pd[mt][r];
                    }
        }
        __syncthreads();
        #pragma unroll
        for (int mt = 0; mt < 4; mt++)
            #pragma unroll
            for (int r = 0; r < 4; r++) {
                int row = mt * 16 + q * 4 + r;
                A[row * OP + w * 32 + lm]      = (f16)acc[mt][0][r];
                A[row * OP + w * 32 + 16 + lm] = (f16)acc[mt][1][r];
            }
        if (MODE == 2 && tid < 64) {
            int n = base + tid;
            if (n < N_NODES) {
                al_src[n] = part_s[0][tid] + part_s[1][tid] + part_s[2][tid] + part_s[3][tid];
                al_dst[n] = part_d[0][tid] + part_d[1][tid] + part_d[2][tid] + part_d[3][tid];
            }
        }
        __syncthreads();
        #pragma unroll
        for (int i = 0; i < 4; i++) {
            int v = tid + i * 256;
            int row = v >> 4, c8 = v & 15;
            if (base + row < N_NODES) {
                float4 hv = *(const float4*)(&A[row * OP + c8 * 8]);
                *reinterpret_cast<float4*>(reinterpret_cast<char*>(xp) +
                    ((size_t)(base + row) * HID + c8 * 8) * 2) = hv;
            }
        }
    }
}

// ---------------- fused: proj GEMM (blocks < GEMM_BLOCKS) + deg/rank (rest) ----------------
__global__ __launch_bounds__(256) void k_proj_deg(
        const float* __restrict__ x, const f16* __restrict__ Wtp,
        const float* __restrict__ pb, __half* __restrict__ h,
        const int* __restrict__ dst, int* __restrict__ deg, int* __restrict__ rank) {
    if (blockIdx.x < GEMM_BLOCKS) {
        gemm_body<64, 0, float>(x, Wtp, pb, nullptr, nullptr, h, nullptr, nullptr, nullptr,
                                blockIdx.x);
    } else {
        int e = (blockIdx.x - GEMM_BLOCKS) * 256 + threadIdx.x;
        if (e < N_EDGES) rank[e] = atomicAdd(&deg[dst[e]], 1);
    }
}

template <int K, int MODE>
__global__ __launch_bounds__(256) void k_gemm(
        const __half* __restrict__ act, const f16* __restrict__ Wt,
        const float* __restrict__ as_, const float* __restrict__ ad_,
        __half* __restrict__ xp, float* __restrict__ al_src, float* __restrict__ al_dst) {
    gemm_body<K, MODE, __half>(act, Wt, nullptr, as_, ad_, nullptr, xp, al_src, al_dst,
                               blockIdx.x);
}

// ---------------- scans ----------------
__global__ void k_scanA(const int* __restrict__ deg, int* __restrict__ bsum) {
    __shared__ int wsu[4];
    int t = threadIdx.x;
    int i = blockIdx.x * 256 + t;
    int d = (i < N_NODES) ? deg[i] : 0;
    int v = d;
    #pragma unroll
    for (int o = 32; o > 0; o >>= 1) v += __shfl_xor(v, o, 64);
    if ((t & 63) == 0) wsu[t >> 6] = v;
    __syncthreads();
    if (t == 0) bsum[blockIdx.x] = wsu[0] + wsu[1] + wsu[2] + wsu[3];
}

// merged scanB+scanC: each block reduces its bsum prefix redundantly
__global__ void k_scanC2(const int* __restrict__ deg, const int* __restrict__ bsum,
                         int* __restrict__ offs) {
    __shared__ int sc[256];
    __shared__ int wred[4];
    int t = threadIdx.x;
    int b = (t < (int)blockIdx.x) ? bsum[t] : 0;   // blockIdx < SCAN_BLOCKS <= 256
    #pragma unroll
    for (int o = 32; o > 0; o >>= 1) b += __shfl_xor(b, o, 64);
    if ((t & 63) == 0) wred[t >> 6] = b;
    __syncthreads();
    int pre = wred[0] + wred[1] + wred[2] + wred[3];
    int i = blockIdx.x * 256 + t;
    int d = (i < N_NODES) ? deg[i] : 0;
    sc[t] = d;
    __syncthreads();
    for (int o = 1; o < 256; o <<= 1) {
        int v = (t >= o) ? sc[t - o] : 0;
        __syncthreads();
        sc[t] += v;
        __syncthreads();
    }
    if (i < N_NODES) offs[i] = pre + sc[t] - d;
    if (i == 0) offs[N_NODES] = N_EDGES;
}

// ---------------- build packed CSR records (atomic-free, full-line scatter) ----------------
__global__ void k_edge_build(const int* __restrict__ src, const int* __restrict__ dst,
                             const int* __restrict__ rank, const int* __restrict__ offs,
                             const float* __restrict__ ea, const float* __restrict__ WeAe,
                             float4* __restrict__ rec) {
    __shared__ float w[ED * 9];
    __shared__ float4 rs[256][4];
    __shared__ int rp[256];
    int tid = threadIdx.x;
    if (tid < ED * 9) w[tid] = WeAe[tid];
    __syncthreads();
    int e = blockIdx.x * 256 + tid;
    if (e < N_EDGES) {
        float ev[ED];
        const float4* ep4 = reinterpret_cast<const float4*>(ea + (size_t)e * ED);
        #pragma unroll
        for (int q = 0; q < 4; q++) {
            float4 v = ep4[q];
            ev[q * 4 + 0] = v.x; ev[q * 4 + 1] = v.y;
            ev[q * 4 + 2] = v.z; ev[q * 4 + 3] = v.w;
        }
        float r[9];
        #pragma unroll
        for (int j = 0; j < 9; j++) r[j] = 0.f;
        #pragma unroll
        for (int k = 0; k < ED; k++) {
            float evk = ev[k];
            #pragma unroll
            for (int j = 0; j < 9; j++) r[j] += evk * w[k * 9 + j];
        }
        int d = dst[e], s = src[e];
        rp[tid] = offs[d] + rank[e];
        rs[tid][0] = make_float4(r[0], r[1], r[2], r[3]);
        rs[tid][1] = make_float4(r[4], r[5], r[6], r[7]);
        rs[tid][2] = make_float4(r[8], __int_as_float(s), __int_as_float(d), 0.f);
        rs[tid][3] = make_float4(0.f, 0.f, 0.f, 0.f);
    } else {
        rp[tid] = -1;
    }
    __syncthreads();
    int g0 = tid >> 2, q = tid & 3;
    #pragma unroll
    for (int rr = 0; rr < 4; rr++) {
        int g = rr * 64 + g0;
        int p = rp[g];
        if (p >= 0) rec[(size_t)p * 4 + q] = rs[g][q];
    }
}

// ---------------- fused agg: 16 edges in flight/wave; fp16 xp, fp16 residual stream ----------
template <int H, int SLOT>
__global__ void k_node_agg(const int* __restrict__ offs, const float4* __restrict__ rec,
                           const float* __restrict__ al_src, const float* __restrict__ al_dst,
                           const __half* __restrict__ xp, const float* __restrict__ bias,
                           const float* __restrict__ g, const float* __restrict__ be,
                           const __half* __restrict__ hin, __half* __restrict__ hout) {
    int tid = threadIdx.x;
    int wave = tid >> 6;
    int lane = tid & 63;
    int n = blockIdx.x * 4 + wave;
    if (n >= N_NODES) return;
    int e0 = offs[n], e1 = offs[n + 1];
    int side = lane >> 4;              // 0..3
    int cl = lane & 15;
    int c = cl * 8;
    int h = cl >> 2;
    float ald = (H == 4) ? al_dst[n * 4 + h] : al_dst[n];
    float acc[8] = {0.f, 0.f, 0.f, 0.f, 0.f, 0.f, 0.f, 0.f};
    float den = 0.f;

    auto fetchw = [&](int i, int& s, float& wv) {
        if (i < e1) {
            const float* rb = (const float*)(rec + (size_t)i * 4);
            s = __float_as_int(rb[9]);
            float r = (H == 4) ? rb[SLOT * 4 + h] : rb[8];
            float al = ((H == 4) ? al_src[s * 4 + h] : al_src[s]) + ald + r;
            al = (al >= 0.f) ? al : 0.2f * al;
            wv = __expf(al);
        } else { s = 0; wv = 0.f; }
    };
    auto accum = [&](uint4 r, float wv) {
        union { uint4 u; __half2 h2[4]; } t2; t2.u = r;
        #pragma unroll
        for (int j = 0; j < 4; j++) {
            float2 f = __half22float2(t2.h2[j]);
            acc[j * 2]     += wv * f.x;
            acc[j * 2 + 1] += wv * f.y;
        }
        den += wv;
    };

    int i = e0 + side;                 // this side: i, i+4, i+8, ... ; 4 slots, step 16
    int sA, sB, sC, sD; float wA, wB, wC, wD;
    fetchw(i, sA, wA);
    fetchw(i + 4, sB, wB);
    fetchw(i + 8, sC, wC);
    fetchw(i + 12, sD, wD);
    while (i < e1) {
        uint4 rA = *reinterpret_cast<const uint4*>(xp + (size_t)sA * HID + c);
        uint4 rB = *reinterpret_cast<const uint4*>(xp + (size_t)sB * HID + c);
        uint4 rC = *reinterpret_cast<const uint4*>(xp + (size_t)sC * HID + c);
        uint4 rD = *reinterpret_cast<const uint4*>(xp + (size_t)sD * HID + c);
        int tA, tB, tC, tD; float vA, vB, vC, vD;
        fetchw(i + 16, tA, vA);
        fetchw(i + 20, tB, vB);
        fetchw(i + 24, tC, vC);
        fetchw(i + 28, tD, vD);
        accum(rA, wA);
        accum(rB, wB);
        accum(rC, wC);
        accum(rD, wD);
        sA = tA; wA = vA; sB = tB; wB = vB;
        sC = tC; wC = vC; sD = tD; wD = vD;
        i += 16;
    }
    #pragma unroll
    for (int j = 0; j < 8; j++) {
        acc[j] += __shfl_xor(acc[j], 16, 64);
        acc[j] += __shfl_xor(acc[j], 32, 64);
    }
    den += __shfl_xor(den, 16, 64);
    den += __shfl_xor(den, 32, 64);

    float inv = 1.f / (den + 1e-16f);
    float v[8];
    const float4 bv0 = *reinterpret_cast<const float4*>(bias + c);
    const float4 bv1 = *reinterpret_cast<const float4*>(bias + c + 4);
    v[0] = acc[0] * inv + bv0.x; v[1] = acc[1] * inv + bv0.y;
    v[2] = acc[2] * inv + bv0.z; v[3] = acc[3] * inv + bv0.w;
    v[4] = acc[4] * inv + bv1.x; v[5] = acc[5] * inv + bv1.y;
    v[6] = acc[6] * inv + bv1.z; v[7] = acc[7] * inv + bv1.w;
    float s8 = v[0] + v[1] + v[2] + v[3] + v[4] + v[5] + v[6] + v[7];
    #pragma unroll
    for (int o = 8; o > 0; o >>= 1) s8 += __shfl_xor(s8, o, 64);
    float mean = s8 * (1.f / HID);
    float q8 = 0.f;
    float d[8];
    #pragma unroll
    for (int j = 0; j < 8; j++) { d[j] = v[j] - mean; q8 += d[j] * d[j]; }
    #pragma unroll
    for (int o = 8; o > 0; o >>= 1) q8 += __shfl_xor(q8, o, 64);
    float rstd = rsqrtf(q8 * (1.f / HID) + 1e-5f);
    if (side < 2) {                    // side0 -> ch c..c+3, side1 -> c+4..c+7
        int co = c + side * 4;
        int j0 = side * 4;
        const float4 gv  = *reinterpret_cast<const float4*>(g + co);
        const float4 bev = *reinterpret_cast<const float4*>(be + co);
        float y0 = d[j0]     * rstd * gv.x + bev.x;
        float y1 = d[j0 + 1] * rstd * gv.y + bev.y;
        float y2 = d[j0 + 2] * rstd * gv.z + bev.z;
        float y3 = d[j0 + 3] * rstd * gv.w + bev.w;
        y0 = (y0 > 0.f) ? y0 : (__expf(y0) - 1.f);
        y1 = (y1 > 0.f) ? y1 : (__expf(y1) - 1.f);
        y2 = (y2 > 0.f) ? y2 : (__expf(y2) - 1.f);
        y3 = (y3 > 0.f) ? y3 : (__expf(y3) - 1.f);
        uint2 ru = *reinterpret_cast<const uint2*>(hin + (size_t)n * HID + co);
        union { uint2 u; __half2 h2[2]; } tr; tr.u = ru;
        float2 r01 = __half22float2(tr.h2[0]);
        float2 r23 = __half22float2(tr.h2[1]);
        union { uint2 u; __half2 h2[2]; } to;
        to.h2[0] = __floats2half2_rn(y0 + r01.x, y1 + r01.y);
        to.h2[1] = __floats2half2_rn(y2 + r23.x, y3 + r23.y);
        *reinterpret_cast<uint2*>(hout + (size_t)n * HID + co) = to.u;
    }
}

// ---------------- gate MLP + graph bounds, tiled 16 nodes/block ----------------
__global__ void k_gate(const __half* __restrict__ h, const float* __restrict__ gW1,
                       const float* __restrict__ gb1, const float* __restrict__ gW2,
                       const float* __restrict__ gb2, const int* __restrict__ batch,
                       float* __restrict__ gate, int* __restrict__ goff) {
    __shared__ float hs[16][HID];
    int tid = threadIdx.x;
    int base = blockIdx.x * 16;
    if (tid < 16) {
        int n = base + tid;
        int cur = batch[n];
        int prev = (n == 0) ? -1 : batch[n - 1];
        for (int gg = prev + 1; gg <= cur; gg++) goff[gg] = n;
        if (n == N_NODES - 1)
            for (int gg = cur + 1; gg <= NB; gg++) goff[gg] = N_NODES;
    }
    {
        int nn = tid >> 4, k8 = tid & 15;  // 256 threads = 16 rows x 16 chunks of 8
        uint4 hv = *reinterpret_cast<const uint4*>(h + (size_t)(base + nn) * HID + k8 * 8);
        union { uint4 u; __half2 h2[4]; } th; th.u = hv;
        #pragma unroll
        for (int j = 0; j < 4; j++) {
            float2 f = __half22float2(th.h2[j]);
            hs[nn][k8 * 8 + j * 2]     = f.x;
            hs[nn][k8 * 8 + j * 2 + 1] = f.y;
        }
    }
    __syncthreads();
    int c = tid & 63;
    int wave = tid >> 6;
    float acc[4] = {0.f, 0.f, 0.f, 0.f};
    #pragma unroll 8
    for (int k = 0; k < HID; k++) {
        float wv = gW1[k * 64 + c];
        #pragma unroll
        for (int q = 0; q < 4; q++) acc[q] += hs[wave * 4 + q][k] * wv;
    }
    float b1 = gb1[c], w2 = gW2[c];
    float p[4];
    #pragma unroll
    for (int q = 0; q < 4; q++) p[q] = fmaxf(acc[q] + b1, 0.f) * w2;
    #pragma unroll
    for (int o = 32; o > 0; o >>= 1) {
        #pragma unroll
        for (int q = 0; q < 4; q++) p[q] += __shfl_xor(p[q], o, 64);
    }
    if (c == 0) {
        float b2 = gb2[0];
        #pragma unroll
        for (int q = 0; q < 4; q++) gate[base + wave * 4 + q] = p[q] + b2;
    }
}

__global__ void k_gmaxden(const float* __restrict__ gate, const int* __restrict__ goff,
                          float* __restrict__ gmax, float* __restrict__ gden) {
    int b = blockIdx.x;
    int t = threadIdx.x;
    __shared__ float red[256];
    int s = goff[b], e = goff[b + 1];
    float m = -__builtin_inff();
    for (int n = s + t; n < e; n += 256) m = fmaxf(m, gate[n]);
    red[t] = m;
    __syncthreads();
    for (int o = 128; o > 0; o >>= 1) { if (t < o) red[t] = fmaxf(red[t], red[t + o]); __syncthreads(); }
    m = red[0];
    __syncthreads();
    float d = 0.f;
    for (int n = s + t; n < e; n += 256) d += __expf(gate[n] - m);
    red[t] = d;
    __syncthreads();
    for (int o = 128; o > 0; o >>= 1) { if (t < o) red[t] += red[t + o]; __syncthreads(); }
    if (t == 0) { gmax[b] = m; gden[b] = red[0]; }
}

__global__ void k_pool(const __half* __restrict__ h, const float* __restrict__ gate,
                       const float* __restrict__ gmax, const float* __restrict__ gden,
                       const int* __restrict__ goff, float* __restrict__ pooled) {
    int b = blockIdx.x;
    int part = blockIdx.y;
    int c = threadIdx.x;
    int s = goff[b], e = goff[b + 1];
    float m = gmax[b];
    float dinv = 1.f / (gden[b] + 1e-16f);
    float acc = 0.f;
    for (int n = s + part; n < e; n += POOL_SPLIT) {
        float att = __expf(gate[n] - m) * dinv;
        acc += att * __half2float(h[(size_t)n * HID + c]);
    }
    atomicAdd(&pooled[b * HID + c], acc);
}

__global__ void k_head(const float* __restrict__ pooled, const float* __restrict__ cW1,
                       const float* __restrict__ cb1, const float* __restrict__ cW2,
                       const float* __restrict__ cb2, float* __restrict__ out) {
    int b = blockIdx.x;
    int t = threadIdx.x;
    __shared__ float pr[HID];
    __shared__ float tr[64];
    pr[t] = pooled[b * HID + t];
    pr[t + 64] = pooled[b * HID + t + 64];
    __syncthreads();
    float a = cb1[t];
    #pragma unroll 8
    for (int k = 0; k < HID; k++) a += pr[k] * cW1[k * 64 + t];
    tr[t] = fmaxf(a, 0.f);
    __syncthreads();
    if (t < NC) {
        float o = cb2[t];
        #pragma unroll
        for (int k = 0; k < 64; k++) o += tr[k] * cW2[k * NC + t];
        out[b * NC + t] = o;
    }
}

extern "C" void kernel_launch(void* const* d_in, const int* in_sizes, int n_in,
                              void* d_out, int out_size, void* d_ws, size_t ws_size,
                              hipStream_t stream) {
    (void)in_sizes; (void)n_in; (void)out_size; (void)ws_size;
    const float* x     = (const float*)d_in[0];
    const int*   ei    = (const int*)d_in[1];
    const float* ea    = (const float*)d_in[2];
    const int*   batch = (const int*)d_in[3];
    const float* pW    = (const float*)d_in[4];
    const float* pb    = (const float*)d_in[5];
    const float *W[3], *as_[3], *ad_[3], *ae_[3], *We[3], *bb[3], *gg[3], *be[3];
    for (int l = 0; l < 3; l++) {
        int base = 6 + 8 * l;
        W[l]   = (const float*)d_in[base + 0];
        as_[l] = (const float*)d_in[base + 1];
        ad_[l] = (const float*)d_in[base + 2];
        ae_[l] = (const float*)d_in[base + 3];
        We[l]  = (const float*)d_in[base + 4];
        bb[l]  = (const float*)d_in[base + 5];
        gg[l]  = (const float*)d_in[base + 6];
        be[l]  = (const float*)d_in[base + 7];
    }
    const float* gW1 = (const float*)d_in[30];
    const float* gb1 = (const float*)d_in[31];
    const float* gW2 = (const float*)d_in[32];
    const float* gb2 = (const float*)d_in[33];
    const float* cW1 = (const float*)d_in[34];
    const float* cb1 = (const float*)d_in[35];
    const float* cW2 = (const float*)d_in[36];
    const float* cb2 = (const float*)d_in[37];
    float* out = (float*)d_out;

    char* p = (char*)d_ws;
    auto take = [&](size_t bytes) -> char* {
        char* r = p;
        p += (bytes + 255) & ~(size_t)255;
        return r;
    };
    __half* h0      = (__half*)take((size_t)N_NODES * HID * 2);
    __half* h1      = (__half*)take((size_t)N_NODES * HID * 2);
    __half* xp      = (__half*)take((size_t)N_NODES * HID * 2);
    float*  al_src  = (float*)take((size_t)N_NODES * 4 * 4);
    float*  al_dst  = (float*)take((size_t)N_NODES * 4 * 4);
    float4* rec     = (float4*)take((size_t)N_EDGES * 64);
    int*    deg     = (int*)take((size_t)N_NODES * 4);
    int*    offs    = (int*)take((size_t)(N_NODES + 1) * 4);
    int*    rank    = (int*)take((size_t)N_EDGES * 4);
    int*    bsum    = (int*)take(256 * 4);
    float*  WeAe    = (float*)take(ED * 9 * 4);
    float*  gate    = (float*)take((size_t)N_NODES * 4);
    float*  gmax    = (float*)take(NB * 4);
    float*  gden    = (float*)take(NB * 4);
    int*    goff    = (int*)take((NB + 1) * 4);
    float*  pooled  = (float*)take(NB * HID * 4);
    f16*    Wtp     = (f16*)take(128 * 64 * 2);
    f16*    Wt0     = (f16*)take(128 * 128 * 2);
    f16*    Wt1     = (f16*)take(128 * 128 * 2);
    f16*    Wt2     = (f16*)take(128 * 128 * 2);
    f16*    Wt[3]   = {Wt0, Wt1, Wt2};

    const int* src = ei;
    const int* dst = ei + N_EDGES;

    k_setup<<<256, 256, 0, stream>>>(pW, W[0], W[1], W[2], We[0], ae_[0], We[1], ae_[1],
                                     We[2], ae_[2], deg, pooled, WeAe, Wtp, Wt0, Wt1, Wt2);
    k_proj_deg<<<GEMM_BLOCKS + DEG_BLOCKS, 256, 0, stream>>>(x, Wtp, pb, h0, dst, deg, rank);
    k_scanA<<<SCAN_BLOCKS, 256, 0, stream>>>(deg, bsum);
    k_scanC2<<<SCAN_BLOCKS, 256, 0, stream>>>(deg, bsum, offs);
    k_edge_build<<<DEG_BLOCKS, 256, 0, stream>>>(src, dst, rank, offs, ea, WeAe, rec);

    __half* hc = h0;
    __half* hn = h1;
    // layer 0
    k_gemm<128, 1><<<GEMM_BLOCKS, 256, 0, stream>>>(hc, Wt[0], as_[0], ad_[0], xp, al_src, al_dst);
    k_node_agg<4, 0><<<(N_NODES + 3) / 4, 256, 0, stream>>>(offs, rec, al_src, al_dst, xp,
                                                            bb[0], gg[0], be[0], hc, hn);
    { __half* t = hc; hc = hn; hn = t; }
    // layer 1
    k_gemm<128, 1><<<GEMM_BLOCKS, 256, 0, stream>>>(hc, Wt[1], as_[1], ad_[1], xp, al_src, al_dst);
    k_node_agg<4, 1><<<(N_NODES + 3) / 4, 256, 0, stream>>>(offs, rec, al_src, al_dst, xp,
                                                            bb[1], gg[1], be[1], hc, hn);
    { __half* t = hc; hc = hn; hn = t; }
    // layer 2
    k_gemm<128, 2><<<GEMM_BLOCKS, 256, 0, stream>>>(hc, Wt[2], as_[2], ad_[2], xp, al_src, al_dst);
    k_node_agg<1, 0><<<(N_NODES + 3) / 4, 256, 0, stream>>>(offs, rec, al_src, al_dst, xp,
                                                            bb[2], gg[2], be[2], hc, hn);
    { __half* t = hc; hc = hn; hn = t; }

    k_gate<<<N_NODES / 16, 256, 0, stream>>>(hc, gW1, gb1, gW2, gb2, batch, gate, goff);
    k_gmaxden<<<NB, 256, 0, stream>>>(gate, goff, gmax, gden);
    k_pool<<<dim3(NB, POOL_SPLIT), HID, 0, stream>>>(hc, gate, gmax, gden, goff, pooled);
    k_head<<<NB, 64, 0, stream>>>(pooled, cW1, cb1, cW2, cb2, out);
}

// Round 11
// 479.520 us; speedup vs baseline: 1.2080x; 1.0093x over previous
//
#include <hip/hip_runtime.h>
#include <hip/hip_fp16.h>
#include <math.h>

#define N_NODES 50000
#define N_EDGES 800000
#define NB      64
#define ND      64
#define ED      16
#define HID     128
#define NC      6
#define POOL_SPLIT 32
#define SCAN_BLOCKS ((N_NODES + 255) / 256)   // 196
#define GEMM_BLOCKS ((N_NODES + 63) / 64)     // 782
#define DEG_BLOCKS  ((N_EDGES + 255) / 256)   // 3125

typedef _Float16 f16;
typedef f16  half8  __attribute__((ext_vector_type(8)));
typedef float floatx4 __attribute__((ext_vector_type(4)));

// ---------------- setup: zero deg+pooled + WeAe + fp16 weight transpose ----------------
__global__ void k_setup(const float* __restrict__ pW, const float* __restrict__ W0,
                        const float* __restrict__ W1, const float* __restrict__ W2,
                        const float* __restrict__ We0, const float* __restrict__ ae0,
                        const float* __restrict__ We1, const float* __restrict__ ae1,
                        const float* __restrict__ We2, const float* __restrict__ ae2,
                        int* __restrict__ deg, float* __restrict__ pooled,
                        float* __restrict__ WeAe,
                        f16* __restrict__ Wtp, f16* __restrict__ Wt0,
                        f16* __restrict__ Wt1, f16* __restrict__ Wt2) {
    int i = blockIdx.x * 256 + threadIdx.x;
    if (i < N_NODES) deg[i] = 0;
    if (i < NB * HID) pooled[i] = 0.f;
    if (i < 128 * 64) {
        int n = i / 64, k = i % 64;
        Wtp[i] = (f16)pW[k * 128 + n];
    }
    if (i < 128 * 128) {
        int n = i / 128, k = i % 128;
        Wt0[i] = (f16)W0[k * 128 + n];
        Wt1[i] = (f16)W1[k * 128 + n];
        Wt2[i] = (f16)W2[k * 128 + n];
    }
    if (i >= 60000 && i < 60144) {
        int t = i - 60000;
        if (t < 64) {
            int k = t >> 2, h = t & 3;
            float s = 0.f;
            for (int c = 0; c < 32; c++) s += We0[k * HID + h * 32 + c] * ae0[h * 32 + c];
            WeAe[k * 9 + h] = s;
        } else if (t < 128) {
            int tt = t - 64;
            int k = tt >> 2, h = tt & 3;
            float s = 0.f;
            for (int c = 0; c < 32; c++) s += We1[k * HID + h * 32 + c] * ae1[h * 32 + c];
            WeAe[k * 9 + 4 + h] = s;
        } else {
            int k = t - 128;
            float s = 0.f;
            for (int c = 0; c < HID; c++) s += We2[k * HID + c] * ae2[c];
            WeAe[k * 9 + 8] = s;
        }
    }
}

// ---------------- MFMA GEMM body: out = act[M,K] @ W[K,128] ----------------
template <int K, int MODE, typename AT>
__device__ __forceinline__ void gemm_body(
        const AT* __restrict__ act, const f16* __restrict__ Wt,
        const float* __restrict__ bias, const float* __restrict__ as_,
        const float* __restrict__ ad_, __half* __restrict__ hout,
        __half* __restrict__ xp, float* __restrict__ al_src,
        float* __restrict__ al_dst, int blk) {
    constexpr int KP = K + 8;
    constexpr int OP = HID + 8;
    __shared__ __align__(16) f16 A[64 * OP];
    __shared__ float part_s[4][64];
    __shared__ float part_d[4][64];
    int tid = threadIdx.x;
    int base = blk * 64;

    if constexpr (sizeof(AT) == 4) {
        constexpr int NV = 64 * (K / 4) / 256;
        #pragma unroll
        for (int i = 0; i < NV; i++) {
            int v = tid + i * 256;
            int row = v / (K / 4), k4 = v % (K / 4);
            float4 xv = make_float4(0.f, 0.f, 0.f, 0.f);
            if (base + row < N_NODES)
                xv = *(const float4*)((const float*)act + (size_t)(base + row) * K + k4 * 4);
            f16* dp = &A[row * KP + k4 * 4];
            dp[0] = (f16)xv.x; dp[1] = (f16)xv.y; dp[2] = (f16)xv.z; dp[3] = (f16)xv.w;
        }
    } else {
        constexpr int NV = 64 * (K / 8) / 256;
        #pragma unroll
        for (int i = 0; i < NV; i++) {
            int v = tid + i * 256;
            int row = v / (K / 8), k8 = v % (K / 8);
            uint4 xv = make_uint4(0, 0, 0, 0);
            if (base + row < N_NODES)
                xv = *(const uint4*)((const __half*)act + (size_t)(base + row) * K + k8 * 8);
            *(uint4*)(&A[row * KP + k8 * 8]) = xv;
        }
    }
    __syncthreads();

    int w = tid >> 6, l = tid & 63;
    int lm = l & 15, q = l >> 4;
    floatx4 acc[4][2];
    #pragma unroll
    for (int mt = 0; mt < 4; mt++)
        #pragma unroll
        for (int j = 0; j < 2; j++)
            acc[mt][j] = (floatx4){0.f, 0.f, 0.f, 0.f};

    #pragma unroll
    for (int kt = 0; kt < K / 32; kt++) {
        int ko = kt * 32 + q * 8;
        half8 b0 = *(const half8*)(Wt + (size_t)(w * 32 + lm) * K + ko);
        half8 b1 = *(const half8*)(Wt + (size_t)(w * 32 + 16 + lm) * K + ko);
        #pragma unroll
        for (int mt = 0; mt < 4; mt++) {
            half8 a = *(const half8*)(&A[(mt * 16 + lm) * KP + ko]);
            acc[mt][0] = __builtin_amdgcn_mfma_f32_16x16x32_f16(a, b0, acc[mt][0], 0, 0, 0);
            acc[mt][1] = __builtin_amdgcn_mfma_f32_16x16x32_f16(a, b1, acc[mt][1], 0, 0, 0);
        }
    }

    if (MODE == 0) {
        float b0 = bias[w * 32 + lm];
        float b1 = bias[w * 32 + 16 + lm];
        __syncthreads();
        #pragma unroll
        for (int mt = 0; mt < 4; mt++)
            #pragma unroll
            for (int r = 0; r < 4; r++) {
                int row = mt * 16 + q * 4 + r;
                A[row * OP + w * 32 + lm]      = (f16)fmaxf(acc[mt][0][r] + b0, 0.f);
                A[row * OP + w * 32 + 16 + lm] = (f16)fmaxf(acc[mt][1][r] + b1, 0.f);
            }
        __syncthreads();
        #pragma unroll
        for (int i = 0; i < 4; i++) {
            int v = tid + i * 256;
            int row = v >> 4, c8 = v & 15;
            if (base + row < N_NODES) {
                float4 hv = *(const float4*)(&A[row * OP + c8 * 8]);
                *reinterpret_cast<float4*>(reinterpret_cast<char*>(hout) +
                    ((size_t)(base + row) * HID + c8 * 8) * 2) = hv;
            }
        }
    } else {
        float a0 = as_[w * 32 + lm], a1 = as_[w * 32 + 16 + lm];
        float e0 = ad_[w * 32 + lm], e1 = ad_[w * 32 + 16 + lm];
        float ps[4][4], pd[4][4];
        #pragma unroll
        for (int mt = 0; mt < 4; mt++)
            #pragma unroll
            for (int r = 0; r < 4; r++) {
                ps[mt][r] = acc[mt][0][r] * a0 + acc[mt][1][r] * a1;
                pd[mt][r] = acc[mt][0][r] * e0 + acc[mt][1][r] * e1;
            }
        #pragma unroll
        for (int off = 1; off < 16; off <<= 1)
            #pragma unroll
            for (int mt = 0; mt < 4; mt++)
                #pragma unroll
                for (int r = 0; r < 4; r++) {
                    ps[mt][r] += __shfl_xor(ps[mt][r], off, 64);
                    pd[mt][r] += __shfl_xor(pd[mt][r], off, 64);
                }
        if (MODE == 1) {
            if (lm == 0)
                #pragma unroll
                for (int mt = 0; mt < 4; mt++)
                    #pragma unroll
                    for (int r = 0; r < 4; r++) {
                        int n = base + mt * 16 + q * 4 + r;
                        if (n < N_NODES) {
                            al_src[n * 4 + w] = ps[mt][r];
                            al_dst[n * 4 + w] = pd[mt][r];
                        }
                    }
        } else {
            if (lm == 0)
                #pragma unroll
                for (int mt = 0; mt < 4; mt++)
                    #pragma unroll
                    for (int r = 0; r < 4; r++) {
                        part_s[w][mt * 16 + q * 4 + r] = ps[mt][r];
                        part_d[w][mt * 16 + q * 4 + r] = pd[mt][r];
                    }
        }
        __syncthreads();
        #pragma unroll
        for (int mt = 0; mt < 4; mt++)
            #pragma unroll
            for (int r = 0; r < 4; r++) {
                int row = mt * 16 + q * 4 + r;
                A[row * OP + w * 32 + lm]      = (f16)acc[mt][0][r];
                A[row * OP + w * 32 + 16 + lm] = (f16)acc[mt][1][r];
            }
        if (MODE == 2 && tid < 64) {
            int n = base + tid;
            if (n < N_NODES) {
                al_src[n] = part_s[0][tid] + part_s[1][tid] + part_s[2][tid] + part_s[3][tid];
                al_dst[n] = part_d[0][tid] + part_d[1][tid] + part_d[2][tid] + part_d[3][tid];
            }
        }
        __syncthreads();
        #pragma unroll
        for (int i = 0; i < 4; i++) {
            int v = tid + i * 256;
            int row = v >> 4, c8 = v & 15;
            if (base + row < N_NODES) {
                float4 hv = *(const float4*)(&A[row * OP + c8 * 8]);
                *reinterpret_cast<float4*>(reinterpret_cast<char*>(xp) +
                    ((size_t)(base + row) * HID + c8 * 8) * 2) = hv;
            }
        }
    }
}

// ---------------- fused: proj GEMM + deg/rank ----------------
__global__ __launch_bounds__(256) void k_proj_deg(
        const float* __restrict__ x, const f16* __restrict__ Wtp,
        const float* __restrict__ pb, __half* __restrict__ h,
        const int* __restrict__ dst, int* __restrict__ deg, int* __restrict__ rank) {
    if (blockIdx.x < GEMM_BLOCKS) {
        gemm_body<64, 0, float>(x, Wtp, pb, nullptr, nullptr, h, nullptr, nullptr, nullptr,
                                blockIdx.x);
    } else {
        int e = (blockIdx.x - GEMM_BLOCKS) * 256 + threadIdx.x;
        if (e < N_EDGES) rank[e] = atomicAdd(&deg[dst[e]], 1);
    }
}

template <int K, int MODE>
__global__ __launch_bounds__(256) void k_gemm(
        const __half* __restrict__ act, const f16* __restrict__ Wt,
        const float* __restrict__ as_, const float* __restrict__ ad_,
        __half* __restrict__ xp, float* __restrict__ al_src, float* __restrict__ al_dst) {
    gemm_body<K, MODE, __half>(act, Wt, nullptr, as_, ad_, nullptr, xp, al_src, al_dst,
                               blockIdx.x);
}

// ---------------- scans ----------------
__global__ void k_scanA(const int* __restrict__ deg, int* __restrict__ bsum) {
    __shared__ int wsu[4];
    int t = threadIdx.x;
    int i = blockIdx.x * 256 + t;
    int d = (i < N_NODES) ? deg[i] : 0;
    int v = d;
    #pragma unroll
    for (int o = 32; o > 0; o >>= 1) v += __shfl_xor(v, o, 64);
    if ((t & 63) == 0) wsu[t >> 6] = v;
    __syncthreads();
    if (t == 0) bsum[blockIdx.x] = wsu[0] + wsu[1] + wsu[2] + wsu[3];
}

__global__ void k_scanC2(const int* __restrict__ deg, const int* __restrict__ bsum,
                         int* __restrict__ offs) {
    __shared__ int sc[256];
    __shared__ int wred[4];
    int t = threadIdx.x;
    int b = (t < (int)blockIdx.x) ? bsum[t] : 0;
    #pragma unroll
    for (int o = 32; o > 0; o >>= 1) b += __shfl_xor(b, o, 64);
    if ((t & 63) == 0) wred[t >> 6] = b;
    __syncthreads();
    int pre = wred[0] + wred[1] + wred[2] + wred[3];
    int i = blockIdx.x * 256 + t;
    int d = (i < N_NODES) ? deg[i] : 0;
    sc[t] = d;
    __syncthreads();
    for (int o = 1; o < 256; o <<= 1) {
        int v = (t >= o) ? sc[t - o] : 0;
        __syncthreads();
        sc[t] += v;
        __syncthreads();
    }
    if (i < N_NODES) offs[i] = pre + sc[t] - d;
    if (i == 0) offs[N_NODES] = N_EDGES;
}

// ---------------- build packed CSR records (atomic-free, full-line scatter) ----------------
__global__ void k_edge_build(const int* __restrict__ src, const int* __restrict__ dst,
                             const int* __restrict__ rank, const int* __restrict__ offs,
                             const float* __restrict__ ea, const float* __restrict__ WeAe,
                             float4* __restrict__ rec) {
    __shared__ float w[ED * 9];
    __shared__ float4 rs[256][4];
    __shared__ int rp[256];
    int tid = threadIdx.x;
    if (tid < ED * 9) w[tid] = WeAe[tid];
    __syncthreads();
    int e = blockIdx.x * 256 + tid;
    if (e < N_EDGES) {
        float ev[ED];
        const float4* ep4 = reinterpret_cast<const float4*>(ea + (size_t)e * ED);
        #pragma unroll
        for (int q = 0; q < 4; q++) {
            float4 v = ep4[q];
            ev[q * 4 + 0] = v.x; ev[q * 4 + 1] = v.y;
            ev[q * 4 + 2] = v.z; ev[q * 4 + 3] = v.w;
        }
        float r[9];
        #pragma unroll
        for (int j = 0; j < 9; j++) r[j] = 0.f;
        #pragma unroll
        for (int k = 0; k < ED; k++) {
            float evk = ev[k];
            #pragma unroll
            for (int j = 0; j < 9; j++) r[j] += evk * w[k * 9 + j];
        }
        int d = dst[e], s = src[e];
        rp[tid] = offs[d] + rank[e];
        rs[tid][0] = make_float4(r[0], r[1], r[2], r[3]);
        rs[tid][1] = make_float4(r[4], r[5], r[6], r[7]);
        rs[tid][2] = make_float4(r[8], __int_as_float(s), __int_as_float(d), 0.f);
        rs[tid][3] = make_float4(0.f, 0.f, 0.f, 0.f);
    } else {
        rp[tid] = -1;
    }
    __syncthreads();
    int g0 = tid >> 2, q = tid & 3;
    #pragma unroll
    for (int rr = 0; rr < 4; rr++) {
        int g = rr * 64 + g0;
        int p = rp[g];
        if (p >= 0) rec[(size_t)p * 4 + q] = rs[g][q];
    }
}

// ---------------- fused agg v2: LDS-staged deduplicated weights + gather + LN + ELU + res ----
// wave per node. Phase A: chunk of 16 edges (H=4) -> lane j computes weight of
// (edge j>>2, head j&3) exactly once; stores w + src to per-wave LDS.
// Phase B: branchless gather, 16 edges in flight (4 sides x 4 slots).
template <int H, int SLOT>
__global__ void k_node_agg(const int* __restrict__ offs, const float4* __restrict__ rec,
                           const float* __restrict__ al_src, const float* __restrict__ al_dst,
                           const __half* __restrict__ xp, const float* __restrict__ bias,
                           const float* __restrict__ g, const float* __restrict__ be,
                           const __half* __restrict__ hin, __half* __restrict__ hout) {
    __shared__ float ws[4][64];
    __shared__ int   ss[4][64];
    int tid = threadIdx.x;
    int wave = tid >> 6;
    int lane = tid & 63;
    int n = blockIdx.x * 4 + wave;
    if (n >= N_NODES) return;
    int e0 = offs[n], e1 = offs[n + 1];
    int side = lane >> 4;              // 0..3
    int cl = lane & 15;
    int c = cl * 8;
    int h = cl >> 2;                   // consumer head
    // producer (phase A) mapping
    int pa_h   = (H == 4) ? (lane & 3) : 0;
    int pa_off = (H == 4) ? (lane >> 2) : lane;
    float pa_ald = (H == 4) ? al_dst[n * 4 + pa_h] : al_dst[n];
    const int CHUNK = (H == 4) ? 16 : 64;

    float acc[8] = {0.f, 0.f, 0.f, 0.f, 0.f, 0.f, 0.f, 0.f};
    float den = 0.f;

    auto accum = [&](uint4 r, float wv) {
        union { uint4 u; __half2 h2[4]; } t2; t2.u = r;
        #pragma unroll
        for (int j = 0; j < 4; j++) {
            float2 f = __half22float2(t2.h2[j]);
            acc[j * 2]     += wv * f.x;
            acc[j * 2 + 1] += wv * f.y;
        }
        den += wv;
    };

    for (int cb = e0; cb < e1; cb += CHUNK) {
        // ---- phase A: one weight per (edge, head), no redundancy ----
        int i = cb + pa_off;
        float wv = 0.f;
        int s = 0;
        if (i < e1) {
            const float* rb = (const float*)(rec + (size_t)i * 4);
            s = __float_as_int(rb[9]);
            float r = (H == 4) ? rb[SLOT * 4 + pa_h] : rb[8];
            float al = ((H == 4) ? al_src[s * 4 + pa_h] : al_src[s]) + pa_ald + r;
            al = (al >= 0.f) ? al : 0.2f * al;
            wv = __expf(al);
        }
        ws[wave][lane] = wv;           // H=4 layout: [eloc*4 + h]; H=1: [eloc]
        if (H == 4) {
            if (pa_h == 0) ss[wave][pa_off] = s;
        } else {
            ss[wave][lane] = s;
        }
        // wave-synchronous: same wave wrote, same wave reads (lgkmcnt enforced)
        // ---- phase B: branchless gather, 4 slots per side in flight ----
        if (H == 4) {
            #pragma unroll
            for (int k = 0; k < 4; k++) {
                int eloc = side + 4 * k;
                int sg = ss[wave][eloc];
                float wk = ws[wave][eloc * 4 + h];
                uint4 r = *reinterpret_cast<const uint4*>(xp + (size_t)sg * HID + c);
                accum(r, wk);
            }
        } else {
            #pragma unroll
            for (int kk = 0; kk < 4; kk++) {
                #pragma unroll
                for (int k = 0; k < 4; k++) {
                    int eloc = side + 4 * (kk * 4 + k);
                    int sg = ss[wave][eloc];
                    float wk = ws[wave][eloc];
                    uint4 r = *reinterpret_cast<const uint4*>(xp + (size_t)sg * HID + c);
                    accum(r, wk);
                }
            }
        }
    }

    #pragma unroll
    for (int j = 0; j < 8; j++) {
        acc[j] += __shfl_xor(acc[j], 16, 64);
        acc[j] += __shfl_xor(acc[j], 32, 64);
    }
    den += __shfl_xor(den, 16, 64);
    den += __shfl_xor(den, 32, 64);

    float inv = 1.f / (den + 1e-16f);
    float v[8];
    const float4 bv0 = *reinterpret_cast<const float4*>(bias + c);
    const float4 bv1 = *reinterpret_cast<const float4*>(bias + c + 4);
    v[0] = acc[0] * inv + bv0.x; v[1] = acc[1] * inv + bv0.y;
    v[2] = acc[2] * inv + bv0.z; v[3] = acc[3] * inv + bv0.w;
    v[4] = acc[4] * inv + bv1.x; v[5] = acc[5] * inv + bv1.y;
    v[6] = acc[6] * inv + bv1.z; v[7] = acc[7] * inv + bv1.w;
    float s8 = v[0] + v[1] + v[2] + v[3] + v[4] + v[5] + v[6] + v[7];
    #pragma unroll
    for (int o = 8; o > 0; o >>= 1) s8 += __shfl_xor(s8, o, 64);
    float mean = s8 * (1.f / HID);
    float q8 = 0.f;
    float d[8];
    #pragma unroll
    for (int j = 0; j < 8; j++) { d[j] = v[j] - mean; q8 += d[j] * d[j]; }
    #pragma unroll
    for (int o = 8; o > 0; o >>= 1) q8 += __shfl_xor(q8, o, 64);
    float rstd = rsqrtf(q8 * (1.f / HID) + 1e-5f);
    if (side < 2) {
        int co = c + side * 4;
        int j0 = side * 4;
        const float4 gv  = *reinterpret_cast<const float4*>(g + co);
        const float4 bev = *reinterpret_cast<const float4*>(be + co);
        float y0 = d[j0]     * rstd * gv.x + bev.x;
        float y1 = d[j0 + 1] * rstd * gv.y + bev.y;
        float y2 = d[j0 + 2] * rstd * gv.z + bev.z;
        float y3 = d[j0 + 3] * rstd * gv.w + bev.w;
        y0 = (y0 > 0.f) ? y0 : (__expf(y0) - 1.f);
        y1 = (y1 > 0.f) ? y1 : (__expf(y1) - 1.f);
        y2 = (y2 > 0.f) ? y2 : (__expf(y2) - 1.f);
        y3 = (y3 > 0.f) ? y3 : (__expf(y3) - 1.f);
        uint2 ru = *reinterpret_cast<const uint2*>(hin + (size_t)n * HID + co);
        union { uint2 u; __half2 h2[2]; } tr; tr.u = ru;
        float2 r01 = __half22float2(tr.h2[0]);
        float2 r23 = __half22float2(tr.h2[1]);
        union { uint2 u; __half2 h2[2]; } to;
        to.h2[0] = __floats2half2_rn(y0 + r01.x, y1 + r01.y);
        to.h2[1] = __floats2half2_rn(y2 + r23.x, y3 + r23.y);
        *reinterpret_cast<uint2*>(hout + (size_t)n * HID + co) = to.u;
    }
}

// ---------------- gate MLP + graph bounds, tiled 16 nodes/block ----------------
__global__ void k_gate(const __half* __restrict__ h, const float* __restrict__ gW1,
                       const float* __restrict__ gb1, const float* __restrict__ gW2,
                       const float* __restrict__ gb2, const int* __restrict__ batch,
                       float* __restrict__ gate, int* __restrict__ goff) {
    __shared__ float hs[16][HID];
    int tid = threadIdx.x;
    int base = blockIdx.x * 16;
    if (tid < 16) {
        int n = base + tid;
        int cur = batch[n];
        int prev = (n == 0) ? -1 : batch[n - 1];
        for (int gg = prev + 1; gg <= cur; gg++) goff[gg] = n;
        if (n == N_NODES - 1)
            for (int gg = cur + 1; gg <= NB; gg++) goff[gg] = N_NODES;
    }
    {
        int nn = tid >> 4, k8 = tid & 15;
        uint4 hv = *reinterpret_cast<const uint4*>(h + (size_t)(base + nn) * HID + k8 * 8);
        union { uint4 u; __half2 h2[4]; } th; th.u = hv;
        #pragma unroll
        for (int j = 0; j < 4; j++) {
            float2 f = __half22float2(th.h2[j]);
            hs[nn][k8 * 8 + j * 2]     = f.x;
            hs[nn][k8 * 8 + j * 2 + 1] = f.y;
        }
    }
    __syncthreads();
    int c = tid & 63;
    int wave = tid >> 6;
    float acc[4] = {0.f, 0.f, 0.f, 0.f};
    #pragma unroll 8
    for (int k = 0; k < HID; k++) {
        float wv = gW1[k * 64 + c];
        #pragma unroll
        for (int q = 0; q < 4; q++) acc[q] += hs[wave * 4 + q][k] * wv;
    }
    float b1 = gb1[c], w2 = gW2[c];
    float p[4];
    #pragma unroll
    for (int q = 0; q < 4; q++) p[q] = fmaxf(acc[q] + b1, 0.f) * w2;
    #pragma unroll
    for (int o = 32; o > 0; o >>= 1) {
        #pragma unroll
        for (int q = 0; q < 4; q++) p[q] += __shfl_xor(p[q], o, 64);
    }
    if (c == 0) {
        float b2 = gb2[0];
        #pragma unroll
        for (int q = 0; q < 4; q++) gate[base + wave * 4 + q] = p[q] + b2;
    }
}

__global__ void k_gmaxden(const float* __restrict__ gate, const int* __restrict__ goff,
                          float* __restrict__ gmax, float* __restrict__ gden) {
    int b = blockIdx.x;
    int t = threadIdx.x;
    __shared__ float red[256];
    int s = goff[b], e = goff[b + 1];
    float m = -__builtin_inff();
    for (int n = s + t; n < e; n += 256) m = fmaxf(m, gate[n]);
    red[t] = m;
    __syncthreads();
    for (int o = 128; o > 0; o >>= 1) { if (t < o) red[t] = fmaxf(red[t], red[t + o]); __syncthreads(); }
    m = red[0];
    __syncthreads();
    float d = 0.f;
    for (int n = s + t; n < e; n += 256) d += __expf(gate[n] - m);
    red[t] = d;
    __syncthreads();
    for (int o = 128; o > 0; o >>= 1) { if (t < o) red[t] += red[t + o]; __syncthreads(); }
    if (t == 0) { gmax[b] = m; gden[b] = red[0]; }
}

__global__ void k_pool(const __half* __restrict__ h, const float* __restrict__ gate,
                       const float* __restrict__ gmax, const float* __restrict__ gden,
                       const int* __restrict__ goff, float* __restrict__ pooled) {
    int b = blockIdx.x;
    int part = blockIdx.y;
    int c = threadIdx.x;
    int s = goff[b], e = goff[b + 1];
    float m = gmax[b];
    float dinv = 1.f / (gden[b] + 1e-16f);
    float acc = 0.f;
    for (int n = s + part; n < e; n += POOL_SPLIT) {
        float att = __expf(gate[n] - m) * dinv;
        acc += att * __half2float(h[(size_t)n * HID + c]);
    }
    atomicAdd(&pooled[b * HID + c], acc);
}

__global__ void k_head(const float* __restrict__ pooled, const float* __restrict__ cW1,
                       const float* __restrict__ cb1, const float* __restrict__ cW2,
                       const float* __restrict__ cb2, float* __restrict__ out) {
    int b = blockIdx.x;
    int t = threadIdx.x;
    __shared__ float pr[HID];
    __shared__ float tr[64];
    pr[t] = pooled[b * HID + t];
    pr[t + 64] = pooled[b * HID + t + 64];
    __syncthreads();
    float a = cb1[t];
    #pragma unroll 8
    for (int k = 0; k < HID; k++) a += pr[k] * cW1[k * 64 + t];
    tr[t] = fmaxf(a, 0.f);
    __syncthreads();
    if (t < NC) {
        float o = cb2[t];
        #pragma unroll
        for (int k = 0; k < 64; k++) o += tr[k] * cW2[k * NC + t];
        out[b * NC + t] = o;
    }
}

extern "C" void kernel_launch(void* const* d_in, const int* in_sizes, int n_in,
                              void* d_out, int out_size, void* d_ws, size_t ws_size,
                              hipStream_t stream) {
    (void)in_sizes; (void)n_in; (void)out_size; (void)ws_size;
    const float* x     = (const float*)d_in[0];
    const int*   ei    = (const int*)d_in[1];
    const float* ea    = (const float*)d_in[2];
    const int*   batch = (const int*)d_in[3];
    const float* pW    = (const float*)d_in[4];
    const float* pb    = (const float*)d_in[5];
    const float *W[3], *as_[3], *ad_[3], *ae_[3], *We[3], *bb[3], *gg[3], *be[3];
    for (int l = 0; l < 3; l++) {
        int base = 6 + 8 * l;
        W[l]   = (const float*)d_in[base + 0];
        as_[l] = (const float*)d_in[base + 1];
        ad_[l] = (const float*)d_in[base + 2];
        ae_[l] = (const float*)d_in[base + 3];
        We[l]  = (const float*)d_in[base + 4];
        bb[l]  = (const float*)d_in[base + 5];
        gg[l]  = (const float*)d_in[base + 6];
        be[l]  = (const float*)d_in[base + 7];
    }
    const float* gW1 = (const float*)d_in[30];
    const float* gb1 = (const float*)d_in[31];
    const float* gW2 = (const float*)d_in[32];
    const float* gb2 = (const float*)d_in[33];
    const float* cW1 = (const float*)d_in[34];
    const float* cb1 = (const float*)d_in[35];
    const float* cW2 = (const float*)d_in[36];
    const float* cb2 = (const float*)d_in[37];
    float* out = (float*)d_out;

    char* p = (char*)d_ws;
    auto take = [&](size_t bytes) -> char* {
        char* r = p;
        p += (bytes + 255) & ~(size_t)255;
        return r;
    };
    __half* h0      = (__half*)take((size_t)N_NODES * HID * 2);
    __half* h1      = (__half*)take((size_t)N_NODES * HID * 2);
    __half* xp      = (__half*)take((size_t)N_NODES * HID * 2);
    float*  al_src  = (float*)take((size_t)N_NODES * 4 * 4);
    float*  al_dst  = (float*)take((size_t)N_NODES * 4 * 4);
    float4* rec     = (float4*)take((size_t)N_EDGES * 64);
    int*    deg     = (int*)take((size_t)N_NODES * 4);
    int*    offs    = (int*)take((size_t)(N_NODES + 1) * 4);
    int*    rank    = (int*)take((size_t)N_EDGES * 4);
    int*    bsum    = (int*)take(256 * 4);
    float*  WeAe    = (float*)take(ED * 9 * 4);
    float*  gate    = (float*)take((size_t)N_NODES * 4);
    float*  gmax    = (float*)take(NB * 4);
    float*  gden    = (float*)take(NB * 4);
    int*    goff    = (int*)take((NB + 1) * 4);
    float*  pooled  = (float*)take(NB * HID * 4);
    f16*    Wtp     = (f16*)take(128 * 64 * 2);
    f16*    Wt0     = (f16*)take(128 * 128 * 2);
    f16*    Wt1     = (f16*)take(128 * 128 * 2);
    f16*    Wt2     = (f16*)take(128 * 128 * 2);
    f16*    Wt[3]   = {Wt0, Wt1, Wt2};

    const int* src = ei;
    const int* dst = ei + N_EDGES;

    k_setup<<<256, 256, 0, stream>>>(pW, W[0], W[1], W[2], We[0], ae_[0], We[1], ae_[1],
                                     We[2], ae_[2], deg, pooled, WeAe, Wtp, Wt0, Wt1, Wt2);
    k_proj_deg<<<GEMM_BLOCKS + DEG_BLOCKS, 256, 0, stream>>>(x, Wtp, pb, h0, dst, deg, rank);
    k_scanA<<<SCAN_BLOCKS, 256, 0, stream>>>(deg, bsum);
    k_scanC2<<<SCAN_BLOCKS, 256, 0, stream>>>(deg, bsum, offs);
    k_edge_build<<<DEG_BLOCKS, 256, 0, stream>>>(src, dst, rank, offs, ea, WeAe, rec);

    __half* hc = h0;
    __half* hn = h1;
    // layer 0
    k_gemm<128, 1><<<GEMM_BLOCKS, 256, 0, stream>>>(hc, Wt[0], as_[0], ad_[0], xp, al_src, al_dst);
    k_node_agg<4, 0><<<(N_NODES + 3) / 4, 256, 0, stream>>>(offs, rec, al_src, al_dst, xp,
                                                            bb[0], gg[0], be[0], hc, hn);
    { __half* t = hc; hc = hn; hn = t; }
    // layer 1
    k_gemm<128, 1><<<GEMM_BLOCKS, 256, 0, stream>>>(hc, Wt[1], as_[1], ad_[1], xp, al_src, al_dst);
    k_node_agg<4, 1><<<(N_NODES + 3) / 4, 256, 0, stream>>>(offs, rec, al_src, al_dst, xp,
                                                            bb[1], gg[1], be[1], hc, hn);
    { __half* t = hc; hc = hn; hn = t; }
    // layer 2
    k_gemm<128, 2><<<GEMM_BLOCKS, 256, 0, stream>>>(hc, Wt[2], as_[2], ad_[2], xp, al_src, al_dst);
    k_node_agg<1, 0><<<(N_NODES + 3) / 4, 256, 0, stream>>>(offs, rec, al_src, al_dst, xp,
                                                            bb[2], gg[2], be[2], hc, hn);
    { __half* t = hc; hc = hn; hn = t; }

    k_gate<<<N_NODES / 16, 256, 0, stream>>>(hc, gW1, gb1, gW2, gb2, batch, gate, goff);
    k_gmaxden<<<NB, 256, 0, stream>>>(gate, goff, gmax, gden);
    k_pool<<<dim3(NB, POOL_SPLIT), HID, 0, stream>>>(hc, gate, gmax, gden, goff, pooled);
    k_head<<<NB, 64, 0, stream>>>(pooled, cW1, cb1, cW2, cb2, out);
}

// Round 12
// 475.180 us; speedup vs baseline: 1.2190x; 1.0091x over previous
//
#include <hip/hip_runtime.h>
#include <hip/hip_fp16.h>
#include <math.h>

#define N_NODES 50000
#define N_EDGES 800000
#define NB      64
#define ND      64
#define ED      16
#define HID     128
#define NC      6
#define POOL_SPLIT 32
#define SCAN_BLOCKS ((N_NODES + 255) / 256)   // 196
#define GEMM_BLOCKS ((N_NODES + 63) / 64)     // 782
#define DEG_BLOCKS  ((N_EDGES + 255) / 256)   // 3125

typedef _Float16 f16;
typedef f16  half8  __attribute__((ext_vector_type(8)));
typedef float floatx4 __attribute__((ext_vector_type(4)));

// ---------------- setup: zero deg+pooled + WeAe + fp16 weight transpose ----------------
__global__ void k_setup(const float* __restrict__ pW, const float* __restrict__ W0,
                        const float* __restrict__ W1, const float* __restrict__ W2,
                        const float* __restrict__ We0, const float* __restrict__ ae0,
                        const float* __restrict__ We1, const float* __restrict__ ae1,
                        const float* __restrict__ We2, const float* __restrict__ ae2,
                        int* __restrict__ deg, float* __restrict__ pooled,
                        float* __restrict__ WeAe,
                        f16* __restrict__ Wtp, f16* __restrict__ Wt0,
                        f16* __restrict__ Wt1, f16* __restrict__ Wt2) {
    int i = blockIdx.x * 256 + threadIdx.x;
    if (i < N_NODES) deg[i] = 0;
    if (i < NB * HID) pooled[i] = 0.f;
    if (i < 128 * 64) {
        int n = i / 64, k = i % 64;
        Wtp[i] = (f16)pW[k * 128 + n];
    }
    if (i < 128 * 128) {
        int n = i / 128, k = i % 128;
        Wt0[i] = (f16)W0[k * 128 + n];
        Wt1[i] = (f16)W1[k * 128 + n];
        Wt2[i] = (f16)W2[k * 128 + n];
    }
    if (i >= 60000 && i < 60144) {
        int t = i - 60000;
        if (t < 64) {
            int k = t >> 2, h = t & 3;
            float s = 0.f;
            for (int c = 0; c < 32; c++) s += We0[k * HID + h * 32 + c] * ae0[h * 32 + c];
            WeAe[k * 9 + h] = s;
        } else if (t < 128) {
            int tt = t - 64;
            int k = tt >> 2, h = tt & 3;
            float s = 0.f;
            for (int c = 0; c < 32; c++) s += We1[k * HID + h * 32 + c] * ae1[h * 32 + c];
            WeAe[k * 9 + 4 + h] = s;
        } else {
            int k = t - 128;
            float s = 0.f;
            for (int c = 0; c < HID; c++) s += We2[k * HID + c] * ae2[c];
            WeAe[k * 9 + 8] = s;
        }
    }
}

// ---------------- MFMA GEMM body: out = act[M,K] @ W[K,128] ----------------
template <int K, int MODE, typename AT>
__device__ __forceinline__ void gemm_body(
        const AT* __restrict__ act, const f16* __restrict__ Wt,
        const float* __restrict__ bias, const float* __restrict__ as_,
        const float* __restrict__ ad_, __half* __restrict__ hout,
        __half* __restrict__ xp, float* __restrict__ al_src,
        float* __restrict__ al_dst, int blk) {
    constexpr int KP = K + 8;
    constexpr int OP = HID + 8;
    __shared__ __align__(16) f16 A[64 * OP];
    __shared__ float part_s[4][64];
    __shared__ float part_d[4][64];
    int tid = threadIdx.x;
    int base = blk * 64;

    if constexpr (sizeof(AT) == 4) {
        constexpr int NV = 64 * (K / 4) / 256;
        #pragma unroll
        for (int i = 0; i < NV; i++) {
            int v = tid + i * 256;
            int row = v / (K / 4), k4 = v % (K / 4);
            float4 xv = make_float4(0.f, 0.f, 0.f, 0.f);
            if (base + row < N_NODES)
                xv = *(const float4*)((const float*)act + (size_t)(base + row) * K + k4 * 4);
            f16* dp = &A[row * KP + k4 * 4];
            dp[0] = (f16)xv.x; dp[1] = (f16)xv.y; dp[2] = (f16)xv.z; dp[3] = (f16)xv.w;
        }
    } else {
        constexpr int NV = 64 * (K / 8) / 256;
        #pragma unroll
        for (int i = 0; i < NV; i++) {
            int v = tid + i * 256;
            int row = v / (K / 8), k8 = v % (K / 8);
            uint4 xv = make_uint4(0, 0, 0, 0);
            if (base + row < N_NODES)
                xv = *(const uint4*)((const __half*)act + (size_t)(base + row) * K + k8 * 8);
            *(uint4*)(&A[row * KP + k8 * 8]) = xv;
        }
    }
    __syncthreads();

    int w = tid >> 6, l = tid & 63;
    int lm = l & 15, q = l >> 4;
    floatx4 acc[4][2];
    #pragma unroll
    for (int mt = 0; mt < 4; mt++)
        #pragma unroll
        for (int j = 0; j < 2; j++)
            acc[mt][j] = (floatx4){0.f, 0.f, 0.f, 0.f};

    #pragma unroll
    for (int kt = 0; kt < K / 32; kt++) {
        int ko = kt * 32 + q * 8;
        half8 b0 = *(const half8*)(Wt + (size_t)(w * 32 + lm) * K + ko);
        half8 b1 = *(const half8*)(Wt + (size_t)(w * 32 + 16 + lm) * K + ko);
        #pragma unroll
        for (int mt = 0; mt < 4; mt++) {
            half8 a = *(const half8*)(&A[(mt * 16 + lm) * KP + ko]);
            acc[mt][0] = __builtin_amdgcn_mfma_f32_16x16x32_f16(a, b0, acc[mt][0], 0, 0, 0);
            acc[mt][1] = __builtin_amdgcn_mfma_f32_16x16x32_f16(a, b1, acc[mt][1], 0, 0, 0);
        }
    }

    if (MODE == 0) {
        float b0 = bias[w * 32 + lm];
        float b1 = bias[w * 32 + 16 + lm];
        __syncthreads();
        #pragma unroll
        for (int mt = 0; mt < 4; mt++)
            #pragma unroll
            for (int r = 0; r < 4; r++) {
                int row = mt * 16 + q * 4 + r;
                A[row * OP + w * 32 + lm]      = (f16)fmaxf(acc[mt][0][r] + b0, 0.f);
                A[row * OP + w * 32 + 16 + lm] = (f16)fmaxf(acc[mt][1][r] + b1, 0.f);
            }
        __syncthreads();
        #pragma unroll
        for (int i = 0; i < 4; i++) {
            int v = tid + i * 256;
            int row = v >> 4, c8 = v & 15;
            if (base + row < N_NODES) {
                float4 hv = *(const float4*)(&A[row * OP + c8 * 8]);
                *reinterpret_cast<float4*>(reinterpret_cast<char*>(hout) +
                    ((size_t)(base + row) * HID + c8 * 8) * 2) = hv;
            }
        }
    } else {
        float a0 = as_[w * 32 + lm], a1 = as_[w * 32 + 16 + lm];
        float e0 = ad_[w * 32 + lm], e1 = ad_[w * 32 + 16 + lm];
        float ps[4][4], pd[4][4];
        #pragma unroll
        for (int mt = 0; mt < 4; mt++)
            #pragma unroll
            for (int r = 0; r < 4; r++) {
                ps[mt][r] = acc[mt][0][r] * a0 + acc[mt][1][r] * a1;
                pd[mt][r] = acc[mt][0][r] * e0 + acc[mt][1][r] * e1;
            }
        #pragma unroll
        for (int off = 1; off < 16; off <<= 1)
            #pragma unroll
            for (int mt = 0; mt < 4; mt++)
                #pragma unroll
                for (int r = 0; r < 4; r++) {
                    ps[mt][r] += __shfl_xor(ps[mt][r], off, 64);
                    pd[mt][r] += __shfl_xor(pd[mt][r], off, 64);
                }
        if (MODE == 1) {
            if (lm == 0)
                #pragma unroll
                for (int mt = 0; mt < 4; mt++)
                    #pragma unroll
                    for (int r = 0; r < 4; r++) {
                        int n = base + mt * 16 + q * 4 + r;
                        if (n < N_NODES) {
                            al_src[n * 4 + w] = ps[mt][r];
                            al_dst[n * 4 + w] = pd[mt][r];
                        }
                    }
        } else {
            if (lm == 0)
                #pragma unroll
                for (int mt = 0; mt < 4; mt++)
                    #pragma unroll
                    for (int r = 0; r < 4; r++) {
                        part_s[w][mt * 16 + q * 4 + r] = ps[mt][r];
                        part_d[w][mt * 16 + q * 4 + r] = pd[mt][r];
                    }
        }
        __syncthreads();
        #pragma unroll
        for (int mt = 0; mt < 4; mt++)
            #pragma unroll
            for (int r = 0; r < 4; r++) {
                int row = mt * 16 + q * 4 + r;
                A[row * OP + w * 32 + lm]      = (f16)acc[mt][0][r];
                A[row * OP + w * 32 + 16 + lm] = (f16)acc[mt][1][r];
            }
        if (MODE == 2 && tid < 64) {
            int n = base + tid;
            if (n < N_NODES) {
                al_src[n] = part_s[0][tid] + part_s[1][tid] + part_s[2][tid] + part_s[3][tid];
                al_dst[n] = part_d[0][tid] + part_d[1][tid] + part_d[2][tid] + part_d[3][tid];
            }
        }
        __syncthreads();
        #pragma unroll
        for (int i = 0; i < 4; i++) {
            int v = tid + i * 256;
            int row = v >> 4, c8 = v & 15;
            if (base + row < N_NODES) {
                float4 hv = *(const float4*)(&A[row * OP + c8 * 8]);
                *reinterpret_cast<float4*>(reinterpret_cast<char*>(xp) +
                    ((size_t)(base + row) * HID + c8 * 8) * 2) = hv;
            }
        }
    }
}

// ---------------- fused: proj GEMM + deg/rank ----------------
__global__ __launch_bounds__(256) void k_proj_deg(
        const float* __restrict__ x, const f16* __restrict__ Wtp,
        const float* __restrict__ pb, __half* __restrict__ h,
        const int* __restrict__ dst, int* __restrict__ deg, int* __restrict__ rank) {
    if (blockIdx.x < GEMM_BLOCKS) {
        gemm_body<64, 0, float>(x, Wtp, pb, nullptr, nullptr, h, nullptr, nullptr, nullptr,
                                blockIdx.x);
    } else {
        int e = (blockIdx.x - GEMM_BLOCKS) * 256 + threadIdx.x;
        if (e < N_EDGES) rank[e] = atomicAdd(&deg[dst[e]], 1);
    }
}

template <int K, int MODE>
__global__ __launch_bounds__(256) void k_gemm(
        const __half* __restrict__ act, const f16* __restrict__ Wt,
        const float* __restrict__ as_, const float* __restrict__ ad_,
        __half* __restrict__ xp, float* __restrict__ al_src, float* __restrict__ al_dst) {
    gemm_body<K, MODE, __half>(act, Wt, nullptr, as_, ad_, nullptr, xp, al_src, al_dst,
                               blockIdx.x);
}

// ---------------- scans ----------------
__global__ void k_scanA(const int* __restrict__ deg, int* __restrict__ bsum) {
    __shared__ int wsu[4];
    int t = threadIdx.x;
    int i = blockIdx.x * 256 + t;
    int d = (i < N_NODES) ? deg[i] : 0;
    int v = d;
    #pragma unroll
    for (int o = 32; o > 0; o >>= 1) v += __shfl_xor(v, o, 64);
    if ((t & 63) == 0) wsu[t >> 6] = v;
    __syncthreads();
    if (t == 0) bsum[blockIdx.x] = wsu[0] + wsu[1] + wsu[2] + wsu[3];
}

__global__ void k_scanC2(const int* __restrict__ deg, const int* __restrict__ bsum,
                         int* __restrict__ offs) {
    __shared__ int sc[256];
    __shared__ int wred[4];
    int t = threadIdx.x;
    int b = (t < (int)blockIdx.x) ? bsum[t] : 0;
    #pragma unroll
    for (int o = 32; o > 0; o >>= 1) b += __shfl_xor(b, o, 64);
    if ((t & 63) == 0) wred[t >> 6] = b;
    __syncthreads();
    int pre = wred[0] + wred[1] + wred[2] + wred[3];
    int i = blockIdx.x * 256 + t;
    int d = (i < N_NODES) ? deg[i] : 0;
    sc[t] = d;
    __syncthreads();
    for (int o = 1; o < 256; o <<= 1) {
        int v = (t >= o) ? sc[t - o] : 0;
        __syncthreads();
        sc[t] += v;
        __syncthreads();
    }
    if (i < N_NODES) offs[i] = pre + sc[t] - d;
    if (i == 0) offs[N_NODES] = N_EDGES;
}

// ---------------- build packed 32B CSR records ----------------
// rec2[2p]   = {h2(r0,r1), h2(r2,r3), h2(r4,r5), h2(r6,r7)}   (L0, L1 logits fp16)
// rec2[2p+1] = {r8 fp32, src, 0, 0}
__global__ void k_edge_build(const int* __restrict__ src, const int* __restrict__ dst,
                             const int* __restrict__ rank, const int* __restrict__ offs,
                             const float* __restrict__ ea, const float* __restrict__ WeAe,
                             uint4* __restrict__ rec2) {
    __shared__ float w[ED * 9];
    __shared__ uint4 rs[256][2];
    __shared__ int rp[256];
    int tid = threadIdx.x;
    if (tid < ED * 9) w[tid] = WeAe[tid];
    __syncthreads();
    int e = blockIdx.x * 256 + tid;
    if (e < N_EDGES) {
        float ev[ED];
        const float4* ep4 = reinterpret_cast<const float4*>(ea + (size_t)e * ED);
        #pragma unroll
        for (int q = 0; q < 4; q++) {
            float4 v = ep4[q];
            ev[q * 4 + 0] = v.x; ev[q * 4 + 1] = v.y;
            ev[q * 4 + 2] = v.z; ev[q * 4 + 3] = v.w;
        }
        float r[9];
        #pragma unroll
        for (int j = 0; j < 9; j++) r[j] = 0.f;
        #pragma unroll
        for (int k = 0; k < ED; k++) {
            float evk = ev[k];
            #pragma unroll
            for (int j = 0; j < 9; j++) r[j] += evk * w[k * 9 + j];
        }
        int d = dst[e], s = src[e];
        rp[tid] = offs[d] + rank[e];
        union { __half2 h; unsigned u; } cv;
        uint4 q0;
        cv.h = __floats2half2_rn(r[0], r[1]); q0.x = cv.u;
        cv.h = __floats2half2_rn(r[2], r[3]); q0.y = cv.u;
        cv.h = __floats2half2_rn(r[4], r[5]); q0.z = cv.u;
        cv.h = __floats2half2_rn(r[6], r[7]); q0.w = cv.u;
        rs[tid][0] = q0;
        rs[tid][1] = make_uint4(__float_as_uint(r[8]), (unsigned)s, 0u, 0u);
    } else {
        rp[tid] = -1;
    }
    __syncthreads();
    // cooperative write: 2 lanes per record -> 32B contiguous
    int g0 = tid >> 1, q = tid & 1;
    #pragma unroll
    for (int rr = 0; rr < 2; rr++) {
        int g = rr * 128 + g0;
        int p = rp[g];
        if (p >= 0) rec2[(size_t)p * 2 + q] = rs[g][q];
    }
}

// ---------------- fused agg (R10 pipelined): 16 edges in flight, compressed rec ----------
template <int H, int SLOT>
__global__ void k_node_agg(const int* __restrict__ offs, const uint4* __restrict__ rec2,
                           const float* __restrict__ al_src, const float* __restrict__ al_dst,
                           const __half* __restrict__ xp, const float* __restrict__ bias,
                           const float* __restrict__ g, const float* __restrict__ be,
                           const __half* __restrict__ hin, __half* __restrict__ hout) {
    int tid = threadIdx.x;
    int wave = tid >> 6;
    int lane = tid & 63;
    int n = blockIdx.x * 4 + wave;
    if (n >= N_NODES) return;
    int e0 = offs[n], e1 = offs[n + 1];
    int side = lane >> 4;              // 0..3
    int cl = lane & 15;
    int c = cl * 8;
    int h = cl >> 2;
    float ald = (H == 4) ? al_dst[n * 4 + h] : al_dst[n];
    float acc[8] = {0.f, 0.f, 0.f, 0.f, 0.f, 0.f, 0.f, 0.f};
    float den = 0.f;

    auto fetchw = [&](int i, int& s, float& wv) {
        if (i < e1) {
            const char* rb = (const char*)rec2 + (size_t)i * 32;
            s = *(const int*)(rb + 20);
            float r;
            if (H == 4) {
                unsigned u = *(const unsigned*)(rb + SLOT * 8 + ((h >> 1) << 2));
                union { unsigned uu; __half2 hh; } cv; cv.uu = u;
                float2 f = __half22float2(cv.hh);
                r = (h & 1) ? f.y : f.x;
            } else {
                r = *(const float*)(rb + 16);
            }
            float al = ((H == 4) ? al_src[s * 4 + h] : al_src[s]) + ald + r;
            al = (al >= 0.f) ? al : 0.2f * al;
            wv = __expf(al);
        } else { s = 0; wv = 0.f; }
    };
    auto accum = [&](uint4 r, float wv) {
        union { uint4 u; __half2 h2[4]; } t2; t2.u = r;
        #pragma unroll
        for (int j = 0; j < 4; j++) {
            float2 f = __half22float2(t2.h2[j]);
            acc[j * 2]     += wv * f.x;
            acc[j * 2 + 1] += wv * f.y;
        }
        den += wv;
    };

    int i = e0 + side;                 // 4 slots per side, step 16
    int sA, sB, sC, sD; float wA, wB, wC, wD;
    fetchw(i, sA, wA);
    fetchw(i + 4, sB, wB);
    fetchw(i + 8, sC, wC);
    fetchw(i + 12, sD, wD);
    while (i < e1) {
        uint4 rA = *reinterpret_cast<const uint4*>(xp + (size_t)sA * HID + c);
        uint4 rB = *reinterpret_cast<const uint4*>(xp + (size_t)sB * HID + c);
        uint4 rC = *reinterpret_cast<const uint4*>(xp + (size_t)sC * HID + c);
        uint4 rD = *reinterpret_cast<const uint4*>(xp + (size_t)sD * HID + c);
        int tA, tB, tC, tD; float vA, vB, vC, vD;
        fetchw(i + 16, tA, vA);
        fetchw(i + 20, tB, vB);
        fetchw(i + 24, tC, vC);
        fetchw(i + 28, tD, vD);
        accum(rA, wA);
        accum(rB, wB);
        accum(rC, wC);
        accum(rD, wD);
        sA = tA; wA = vA; sB = tB; wB = vB;
        sC = tC; wC = vC; sD = tD; wD = vD;
        i += 16;
    }
    #pragma unroll
    for (int j = 0; j < 8; j++) {
        acc[j] += __shfl_xor(acc[j], 16, 64);
        acc[j] += __shfl_xor(acc[j], 32, 64);
    }
    den += __shfl_xor(den, 16, 64);
    den += __shfl_xor(den, 32, 64);

    float inv = 1.f / (den + 1e-16f);
    float v[8];
    const float4 bv0 = *reinterpret_cast<const float4*>(bias + c);
    const float4 bv1 = *reinterpret_cast<const float4*>(bias + c + 4);
    v[0] = acc[0] * inv + bv0.x; v[1] = acc[1] * inv + bv0.y;
    v[2] = acc[2] * inv + bv0.z; v[3] = acc[3] * inv + bv0.w;
    v[4] = acc[4] * inv + bv1.x; v[5] = acc[5] * inv + bv1.y;
    v[6] = acc[6] * inv + bv1.z; v[7] = acc[7] * inv + bv1.w;
    float s8 = v[0] + v[1] + v[2] + v[3] + v[4] + v[5] + v[6] + v[7];
    #pragma unroll
    for (int o = 8; o > 0; o >>= 1) s8 += __shfl_xor(s8, o, 64);
    float mean = s8 * (1.f / HID);
    float q8 = 0.f;
    float d[8];
    #pragma unroll
    for (int j = 0; j < 8; j++) { d[j] = v[j] - mean; q8 += d[j] * d[j]; }
    #pragma unroll
    for (int o = 8; o > 0; o >>= 1) q8 += __shfl_xor(q8, o, 64);
    float rstd = rsqrtf(q8 * (1.f / HID) + 1e-5f);
    if (side < 2) {
        int co = c + side * 4;
        int j0 = side * 4;
        const float4 gv  = *reinterpret_cast<const float4*>(g + co);
        const float4 bev = *reinterpret_cast<const float4*>(be + co);
        float y0 = d[j0]     * rstd * gv.x + bev.x;
        float y1 = d[j0 + 1] * rstd * gv.y + bev.y;
        float y2 = d[j0 + 2] * rstd * gv.z + bev.z;
        float y3 = d[j0 + 3] * rstd * gv.w + bev.w;
        y0 = (y0 > 0.f) ? y0 : (__expf(y0) - 1.f);
        y1 = (y1 > 0.f) ? y1 : (__expf(y1) - 1.f);
        y2 = (y2 > 0.f) ? y2 : (__expf(y2) - 1.f);
        y3 = (y3 > 0.f) ? y3 : (__expf(y3) - 1.f);
        uint2 ru = *reinterpret_cast<const uint2*>(hin + (size_t)n * HID + co);
        union { uint2 u; __half2 h2[2]; } tr; tr.u = ru;
        float2 r01 = __half22float2(tr.h2[0]);
        float2 r23 = __half22float2(tr.h2[1]);
        union { uint2 u; __half2 h2[2]; } to;
        to.h2[0] = __floats2half2_rn(y0 + r01.x, y1 + r01.y);
        to.h2[1] = __floats2half2_rn(y2 + r23.x, y3 + r23.y);
        *reinterpret_cast<uint2*>(hout + (size_t)n * HID + co) = to.u;
    }
}

// ---------------- gate MLP + graph bounds, tiled 16 nodes/block ----------------
__global__ void k_gate(const __half* __restrict__ h, const float* __restrict__ gW1,
                       const float* __restrict__ gb1, const float* __restrict__ gW2,
                       const float* __restrict__ gb2, const int* __restrict__ batch,
                       float* __restrict__ gate, int* __restrict__ goff) {
    __shared__ float hs[16][HID];
    int tid = threadIdx.x;
    int base = blockIdx.x * 16;
    if (tid < 16) {
        int n = base + tid;
        int cur = batch[n];
        int prev = (n == 0) ? -1 : batch[n - 1];
        for (int gg = prev + 1; gg <= cur; gg++) goff[gg] = n;
        if (n == N_NODES - 1)
            for (int gg = cur + 1; gg <= NB; gg++) goff[gg] = N_NODES;
    }
    {
        int nn = tid >> 4, k8 = tid & 15;
        uint4 hv = *reinterpret_cast<const uint4*>(h + (size_t)(base + nn) * HID + k8 * 8);
        union { uint4 u; __half2 h2[4]; } th; th.u = hv;
        #pragma unroll
        for (int j = 0; j < 4; j++) {
            float2 f = __half22float2(th.h2[j]);
            hs[nn][k8 * 8 + j * 2]     = f.x;
            hs[nn][k8 * 8 + j * 2 + 1] = f.y;
        }
    }
    __syncthreads();
    int c = tid & 63;
    int wave = tid >> 6;
    float acc[4] = {0.f, 0.f, 0.f, 0.f};
    #pragma unroll 8
    for (int k = 0; k < HID; k++) {
        float wv = gW1[k * 64 + c];
        #pragma unroll
        for (int q = 0; q < 4; q++) acc[q] += hs[wave * 4 + q][k] * wv;
    }
    float b1 = gb1[c], w2 = gW2[c];
    float p[4];
    #pragma unroll
    for (int q = 0; q < 4; q++) p[q] = fmaxf(acc[q] + b1, 0.f) * w2;
    #pragma unroll
    for (int o = 32; o > 0; o >>= 1) {
        #pragma unroll
        for (int q = 0; q < 4; q++) p[q] += __shfl_xor(p[q], o, 64);
    }
    if (c == 0) {
        float b2 = gb2[0];
        #pragma unroll
        for (int q = 0; q < 4; q++) gate[base + wave * 4 + q] = p[q] + b2;
    }
}

__global__ void k_gmaxden(const float* __restrict__ gate, const int* __restrict__ goff,
                          float* __restrict__ gmax, float* __restrict__ gden) {
    int b = blockIdx.x;
    int t = threadIdx.x;
    __shared__ float red[256];
    int s = goff[b], e = goff[b + 1];
    float m = -__builtin_inff();
    for (int n = s + t; n < e; n += 256) m = fmaxf(m, gate[n]);
    red[t] = m;
    __syncthreads();
    for (int o = 128; o > 0; o >>= 1) { if (t < o) red[t] = fmaxf(red[t], red[t + o]); __syncthreads(); }
    m = red[0];
    __syncthreads();
    float d = 0.f;
    for (int n = s + t; n < e; n += 256) d += __expf(gate[n] - m);
    red[t] = d;
    __syncthreads();
    for (int o = 128; o > 0; o >>= 1) { if (t < o) red[t] += red[t + o]; __syncthreads(); }
    if (t == 0) { gmax[b] = m; gden[b] = red[0]; }
}

__global__ void k_pool(const __half* __restrict__ h, const float* __restrict__ gate,
                       const float* __restrict__ gmax, const float* __restrict__ gden,
                       const int* __restrict__ goff, float* __restrict__ pooled) {
    int b = blockIdx.x;
    int part = blockIdx.y;
    int c = threadIdx.x;
    int s = goff[b], e = goff[b + 1];
    float m = gmax[b];
    float dinv = 1.f / (gden[b] + 1e-16f);
    float acc = 0.f;
    for (int n = s + part; n < e; n += POOL_SPLIT) {
        float att = __expf(gate[n] - m) * dinv;
        acc += att * __half2float(h[(size_t)n * HID + c]);
    }
    atomicAdd(&pooled[b * HID + c], acc);
}

__global__ void k_head(const float* __restrict__ pooled, const float* __restrict__ cW1,
                       const float* __restrict__ cb1, const float* __restrict__ cW2,
                       const float* __restrict__ cb2, float* __restrict__ out) {
    int b = blockIdx.x;
    int t = threadIdx.x;
    __shared__ float pr[HID];
    __shared__ float tr[64];
    pr[t] = pooled[b * HID + t];
    pr[t + 64] = pooled[b * HID + t + 64];
    __syncthreads();
    float a = cb1[t];
    #pragma unroll 8
    for (int k = 0; k < HID; k++) a += pr[k] * cW1[k * 64 + t];
    tr[t] = fmaxf(a, 0.f);
    __syncthreads();
    if (t < NC) {
        float o = cb2[t];
        #pragma unroll
        for (int k = 0; k < 64; k++) o += tr[k] * cW2[k * NC + t];
        out[b * NC + t] = o;
    }
}

extern "C" void kernel_launch(void* const* d_in, const int* in_sizes, int n_in,
                              void* d_out, int out_size, void* d_ws, size_t ws_size,
                              hipStream_t stream) {
    (void)in_sizes; (void)n_in; (void)out_size; (void)ws_size;
    const float* x     = (const float*)d_in[0];
    const int*   ei    = (const int*)d_in[1];
    const float* ea    = (const float*)d_in[2];
    const int*   batch = (const int*)d_in[3];
    const float* pW    = (const float*)d_in[4];
    const float* pb    = (const float*)d_in[5];
    const float *W[3], *as_[3], *ad_[3], *ae_[3], *We[3], *bb[3], *gg[3], *be[3];
    for (int l = 0; l < 3; l++) {
        int base = 6 + 8 * l;
        W[l]   = (const float*)d_in[base + 0];
        as_[l] = (const float*)d_in[base + 1];
        ad_[l] = (const float*)d_in[base + 2];
        ae_[l] = (const float*)d_in[base + 3];
        We[l]  = (const float*)d_in[base + 4];
        bb[l]  = (const float*)d_in[base + 5];
        gg[l]  = (const float*)d_in[base + 6];
        be[l]  = (const float*)d_in[base + 7];
    }
    const float* gW1 = (const float*)d_in[30];
    const float* gb1 = (const float*)d_in[31];
    const float* gW2 = (const float*)d_in[32];
    const float* gb2 = (const float*)d_in[33];
    const float* cW1 = (const float*)d_in[34];
    const float* cb1 = (const float*)d_in[35];
    const float* cW2 = (const float*)d_in[36];
    const float* cb2 = (const float*)d_in[37];
    float* out = (float*)d_out;

    char* p = (char*)d_ws;
    auto take = [&](size_t bytes) -> char* {
        char* r = p;
        p += (bytes + 255) & ~(size_t)255;
        return r;
    };
    __half* h0      = (__half*)take((size_t)N_NODES * HID * 2);
    __half* h1      = (__half*)take((size_t)N_NODES * HID * 2);
    __half* xp      = (__half*)take((size_t)N_NODES * HID * 2);
    float*  al_src  = (float*)take((size_t)N_NODES * 4 * 4);
    float*  al_dst  = (float*)take((size_t)N_NODES * 4 * 4);
    uint4*  rec2    = (uint4*)take((size_t)N_EDGES * 32);
    int*    deg     = (int*)take((size_t)N_NODES * 4);
    int*    offs    = (int*)take((size_t)(N_NODES + 1) * 4);
    int*    rank    = (int*)take((size_t)N_EDGES * 4);
    int*    bsum    = (int*)take(256 * 4);
    float*  WeAe    = (float*)take(ED * 9 * 4);
    float*  gate    = (float*)take((size_t)N_NODES * 4);
    float*  gmax    = (float*)take(NB * 4);
    float*  gden    = (float*)take(NB * 4);
    int*    goff    = (int*)take((NB + 1) * 4);
    float*  pooled  = (float*)take(NB * HID * 4);
    f16*    Wtp     = (f16*)take(128 * 64 * 2);
    f16*    Wt0     = (f16*)take(128 * 128 * 2);
    f16*    Wt1     = (f16*)take(128 * 128 * 2);
    f16*    Wt2     = (f16*)take(128 * 128 * 2);
    f16*    Wt[3]   = {Wt0, Wt1, Wt2};

    const int* src = ei;
    const int* dst = ei + N_EDGES;

    k_setup<<<256, 256, 0, stream>>>(pW, W[0], W[1], W[2], We[0], ae_[0], We[1], ae_[1],
                                     We[2], ae_[2], deg, pooled, WeAe, Wtp, Wt0, Wt1, Wt2);
    k_proj_deg<<<GEMM_BLOCKS + DEG_BLOCKS, 256, 0, stream>>>(x, Wtp, pb, h0, dst, deg, rank);
    k_scanA<<<SCAN_BLOCKS, 256, 0, stream>>>(deg, bsum);
    k_scanC2<<<SCAN_BLOCKS, 256, 0, stream>>>(deg, bsum, offs);
    k_edge_build<<<DEG_BLOCKS, 256, 0, stream>>>(src, dst, rank, offs, ea, WeAe, rec2);

    __half* hc = h0;
    __half* hn = h1;
    // layer 0
    k_gemm<128, 1><<<GEMM_BLOCKS, 256, 0, stream>>>(hc, Wt[0], as_[0], ad_[0], xp, al_src, al_dst);
    k_node_agg<4, 0><<<(N_NODES + 3) / 4, 256, 0, stream>>>(offs, rec2, al_src, al_dst, xp,
                                                            bb[0], gg[0], be[0], hc, hn);
    { __half* t = hc; hc = hn; hn = t; }
    // layer 1
    k_gemm<128, 1><<<GEMM_BLOCKS, 256, 0, stream>>>(hc, Wt[1], as_[1], ad_[1], xp, al_src, al_dst);
    k_node_agg<4, 1><<<(N_NODES + 3) / 4, 256, 0, stream>>>(offs, rec2, al_src, al_dst, xp,
                                                            bb[1], gg[1], be[1], hc, hn);
    { __half* t = hc; hc = hn; hn = t; }
    // layer 2
    k_gemm<128, 2><<<GEMM_BLOCKS, 256, 0, stream>>>(hc, Wt[2], as_[2], ad_[2], xp, al_src, al_dst);
    k_node_agg<1, 0><<<(N_NODES + 3) / 4, 256, 0, stream>>>(offs, rec2, al_src, al_dst, xp,
                                                            bb[2], gg[2], be[2], hc, hn);
    { __half* t = hc; hc = hn; hn = t; }

    k_gate<<<N_NODES / 16, 256, 0, stream>>>(hc, gW1, gb1, gW2, gb2, batch, gate, goff);
    k_gmaxden<<<NB, 256, 0, stream>>>(gate, goff, gmax, gden);
    k_pool<<<dim3(NB, POOL_SPLIT), HID, 0, stream>>>(hc, gate, gmax, gden, goff, pooled);
    k_head<<<NB, 64, 0, stream>>>(pooled, cW1, cb1, cW2, cb2, out);
}